// Round 15
// baseline (3459.995 us; speedup 1.0000x reference)
//
#include <hip/hip_runtime.h>
#include <math.h>

#define NVTC 7
#define VHS 100
#define CHS 30
#define LDP 112         // t1 (fp32) row stride
#define CTW 128         // padded bias length
#define WFRAG_SZ 32768  // shorts per fragment-ordered weight matrix (hi+lo)
// split-bf16 activation row: 512 B = 128 bf16-hi shorts + 128 bf16-lo shorts (cols 100..127 zero)

typedef short short8 __attribute__((ext_vector_type(8)));
typedef float floatx4 __attribute__((ext_vector_type(4)));

#define MFMA(a, b, c) __builtin_amdgcn_mfma_f32_16x16x32_bf16((a), (b), (c), 0, 0, 0)

// async global->LDS DMA, 16B/lane; LDS dest must be wave-uniform base (+ lane*16 implicit)
#define GLOAD16(g, l)                                                              \
  __builtin_amdgcn_global_load_lds((const __attribute__((address_space(1))) void*)(g), \
                                   (__attribute__((address_space(3))) void*)(l), 16, 0, 0)

__device__ __forceinline__ unsigned short f2bf(float f) {
  unsigned u = __float_as_uint(f);
  return (unsigned short)((u + 0x7fffu + ((u >> 16) & 1u)) >> 16);
}
__device__ __forceinline__ float bf2f(unsigned short h) {
  return __uint_as_float((unsigned)h << 16);
}
__device__ __forceinline__ float sigmf(float v) { return 1.f / (1.f + expf(-v)); }

// ---------------- utility kernels ----------------

__global__ void zero_int_kernel(int* __restrict__ p, int n) {
  int i = blockIdx.x * 256 + threadIdx.x;
  if (i < n) p[i] = 0;
}

__global__ void inv_kernel(const float* __restrict__ ind, const float* __restrict__ outd,
                           float* __restrict__ inv_ind, float* __restrict__ inv_outd, int n) {
  int i = blockIdx.x * 256 + threadIdx.x;
  if (i < n) { inv_ind[i] = 1.0f / ind[i]; inv_outd[i] = 1.0f / outd[i]; }
}

// weight -> fragment-ordered split-bf16 (hi plane + lo plane) for 16x16x32 MFMA B-operand
__global__ void wfrag_kernel(const float* __restrict__ src, int srcLD, int colOff,
                             short* __restrict__ dst) {
  int t = blockIdx.x * 256 + threadIdx.x;
  if (t >= 2048) return;
  int lane = t & 63, rest = t >> 6;
  int ct = rest & 7, kc = rest >> 3;
  int col = ct * 16 + (lane & 15);
  int kbase = kc * 32 + (lane >> 4) * 8;
  short8 hv, lv;
  #pragma unroll
  for (int i = 0; i < 8; ++i) {
    int k = kbase + i;
    float v = (k < VHS && col < VHS) ? src[(size_t)k * srcLD + colOff + col] : 0.f;
    unsigned short h16 = f2bf(v);
    hv[i] = (short)h16;
    lv[i] = (short)f2bf(v - bf2f(h16));
  }
  int base = ((kc * 8 + ct) * 2 * 64 + lane) * 8;
  *(short8*)(dst + base)       = hv;
  *(short8*)(dst + base + 512) = lv;
}

__global__ void pad_b_kernel(const float* __restrict__ b1, int off1,
                             const float* b2, int off2, float* __restrict__ dst) {
  int c = threadIdx.x;  // 128 threads
  float v = 0.f;
  if (c < VHS) { v = b1[off1 + c]; if (b2) v += b2[off2 + c]; }
  dst[c] = v;
}

// vs0 = x @ type_vec, written in split-bf16 row format (cols >= 100 zero)
__global__ void init_vs_kernel(const float* __restrict__ x, const float* __restrict__ tv,
                               char* __restrict__ vsp, int N) {
  int node = blockIdx.x, c = threadIdx.x;  // 128 threads
  if (node >= N) return;
  float v = 0.f;
  if (c < VHS) {
    #pragma unroll
    for (int t = 0; t < NVTC; ++t) v += x[(size_t)node * NVTC + t] * tv[t * VHS + c];
  }
  unsigned short hi = f2bf(v);
  unsigned short lo = f2bf(v - bf2f(hi));
  char* rowp = vsp + ((size_t)node << 9);
  *(unsigned short*)(rowp + 2 * c)       = hi;
  *(unsigned short*)(rowp + 256 + 2 * c) = lo;
}

// ---------------- CSR build (deterministic) ----------------

__global__ void hist_kernel(const int* __restrict__ ei, int E, int* hin, int* hout) {
  int e = blockIdx.x * 256 + threadIdx.x;
  if (e < E) {
    atomicAdd(&hout[ei[e]], 1);
    atomicAdd(&hin[ei[E + e]], 1);
  }
}

__global__ void scan_block_kernel(const int* __restrict__ in, int* __restrict__ mid,
                                  int* __restrict__ sums, int n) {
  __shared__ int lds[256];
  int tid = threadIdx.x;
  int base = blockIdx.x * 1024 + tid * 4;
  int v0 = (base + 0 < n) ? in[base + 0] : 0;
  int v1 = (base + 1 < n) ? in[base + 1] : 0;
  int v2 = (base + 2 < n) ? in[base + 2] : 0;
  int v3 = (base + 3 < n) ? in[base + 3] : 0;
  int s = v0 + v1 + v2 + v3;
  lds[tid] = s;
  __syncthreads();
  for (int off = 1; off < 256; off <<= 1) {
    int t = (tid >= off) ? lds[tid - off] : 0;
    __syncthreads();
    lds[tid] += t;
    __syncthreads();
  }
  int excl = lds[tid] - s;
  int e0 = excl + v0, e1 = e0 + v1, e2 = e1 + v2, e3 = e2 + v3;
  if (base + 0 < n) mid[base + 0] = e0;
  if (base + 1 < n) mid[base + 1] = e1;
  if (base + 2 < n) mid[base + 2] = e2;
  if (base + 3 < n) mid[base + 3] = e3;
  if (tid == 255) sums[blockIdx.x] = lds[255];
}

__global__ void scan_sums_kernel(int* sums, int nb) {
  __shared__ int lds[256];
  int tid = threadIdx.x;
  int v = (tid < nb) ? sums[tid] : 0;
  lds[tid] = v;
  __syncthreads();
  for (int off = 1; off < 256; off <<= 1) {
    int t = (tid >= off) ? lds[tid - off] : 0;
    __syncthreads();
    lds[tid] += t;
    __syncthreads();
  }
  if (tid < nb) sums[tid] = lds[tid];
}

__global__ void scan_finalize_kernel(const int* __restrict__ mid, const int* __restrict__ sums,
                                     int* __restrict__ rp, int n) {
  int i = blockIdx.x * 256 + threadIdx.x;
  if (i >= n) return;
  int blk = i >> 10;
  int add = (blk > 0) ? sums[blk - 1] : 0;
  rp[i + 1] = mid[i] + add;
  if (i == 0) rp[0] = 0;
}

__global__ void fill_kernel(const int* __restrict__ ei, int E, int gOff, int sOff,
                            const int* __restrict__ rp, int* cnt, int* col) {
  int e = blockIdx.x * 256 + threadIdx.x;
  if (e >= E) return;
  int v = ei[sOff + e];
  int p = rp[v] + atomicAdd(&cnt[v], 1);
  col[p] = ei[gOff + e];
}

__global__ void sort_rows_kernel(const int* __restrict__ rp, int* col, int n) {
  int v = blockIdx.x * 256 + threadIdx.x;
  if (v >= n) return;
  int a = rp[v], b = rp[v + 1];
  for (int i = a + 1; i < b; ++i) {
    int key = col[i];
    int j = i - 1;
    while (j >= a && col[j] > key) { col[j + 1] = col[j]; --j; }
    col[j + 1] = key;
  }
}

// agg[v] = (sum of m[u] over sorted neighbors) * iv[v], written split-bf16.
__global__ void __launch_bounds__(256)
gather_kernel(const float* __restrict__ m, const int* __restrict__ rp,
              const int* __restrict__ col, const float* __restrict__ iv,
              char* __restrict__ aggp, int N) {
  int v = blockIdx.x * 8 + (threadIdx.x >> 5);
  if (v >= N) return;
  int lane = threadIdx.x & 31;
  char* rowp = aggp + ((size_t)v << 9);
  if (lane < 28) {
    float4 a = make_float4(0.f, 0.f, 0.f, 0.f);
    int s = rp[v], e = rp[v + 1];
    for (int i = s; i < e; ++i) {
      float4 u = ((const float4*)(m + (size_t)col[i] * LDP))[lane];
      a.x += u.x; a.y += u.y; a.z += u.z; a.w += u.w;
    }
    const float sc = iv[v];
    a.x *= sc; a.y *= sc; a.z *= sc; a.w *= sc;
    unsigned short h0 = f2bf(a.x), h1 = f2bf(a.y), h2 = f2bf(a.z), h3 = f2bf(a.w);
    unsigned short l0 = f2bf(a.x - bf2f(h0)), l1 = f2bf(a.y - bf2f(h1));
    unsigned short l2 = f2bf(a.z - bf2f(h2)), l3 = f2bf(a.w - bf2f(h3));
    *(uint2*)(rowp + 8 * lane) =
        make_uint2((unsigned)h0 | ((unsigned)h1 << 16), (unsigned)h2 | ((unsigned)h3 << 16));
    *(uint2*)(rowp + 256 + 8 * lane) =
        make_uint2((unsigned)l0 | ((unsigned)l1 << 16), (unsigned)l2 | ((unsigned)l3 << 16));
  } else {
    *(uint2*)(rowp + 8 * lane)       = make_uint2(0u, 0u);
    *(uint2*)(rowp + 256 + 8 * lane) = make_uint2(0u, 0u);
  }
}

// ---------------- fused MLP (barrier-free, wave-private, pipelined weights) ----------------
// 4 waves x 16 rows; layer-1 A from global split-bf16; LDS 32KB as wave-private handoff.
__global__ void __launch_bounds__(256, 2)
mlp3_kernel(const char* __restrict__ vsp,
            const short* __restrict__ W1f, const short* __restrict__ W2f,
            const short* __restrict__ W3f,
            const float* __restrict__ b1, const float* __restrict__ b2,
            const float* __restrict__ b3, float* __restrict__ OUT, int N) {
  __shared__ __align__(16) char lds[32768];
  char* ldsH = lds;
  char* ldsL = lds + 16384;
  const int lane = threadIdx.x & 63, wave = threadIdx.x >> 6;
  const int lrbase = wave * 16;
  const int row0 = blockIdx.x * 64 + lrbase;
  if (row0 >= N) return;
  const int a_r = lane & 15, a_kg = lane >> 4;

  short8 Fh[4], Fl[4];
  const char* vrow = vsp + (((size_t)(row0 + a_r)) << 9) + (a_kg << 4);
  #pragma unroll
  for (int kc = 0; kc < 4; ++kc) {
    Fh[kc] = *(const short8*)(vrow + kc * 64);
    Fl[kc] = *(const short8*)(vrow + 256 + kc * 64);
  }
  // zero pad slots k=112..127 for this wave's 16 rows (once)
  if (lane < 32) {
    int row = lrbase + (lane >> 1), sl = 14 + (lane & 1);
    int byte = row * 256 + ((sl * 16) ^ ((row & 7) << 4));
    short8 z = {0, 0, 0, 0, 0, 0, 0, 0};
    *(short8*)(ldsH + byte) = z;
    *(short8*)(ldsL + byte) = z;
  }

  floatx4 acc[7];
  short8 wq[2][14];

#define MLP_LAYER(Wf)                                                      \
  {                                                                        \
    _Pragma("unroll") for (int c = 0; c < 7; ++c)                          \
        acc[c] = (floatx4){0.f, 0.f, 0.f, 0.f};                            \
    _Pragma("unroll") for (int c = 0; c < 7; ++c) {                        \
      const int wb0 = (c * 128 + lane) * 8;                                \
      wq[0][2 * c]     = *(const short8*)((Wf) + wb0);                     \
      wq[0][2 * c + 1] = *(const short8*)((Wf) + wb0 + 512);               \
    }                                                                      \
    _Pragma("unroll") for (int kc = 0; kc < 4; ++kc) {                     \
      const int bsel = kc & 1;                                             \
      if (kc < 3) {                                                        \
        _Pragma("unroll") for (int c = 0; c < 7; ++c) {                    \
          const int wbn = (((kc + 1) * 8 + c) * 128 + lane) * 8;           \
          wq[bsel ^ 1][2 * c]     = *(const short8*)((Wf) + wbn);          \
          wq[bsel ^ 1][2 * c + 1] = *(const short8*)((Wf) + wbn + 512);    \
        }                                                                  \
      }                                                                    \
      __builtin_amdgcn_s_setprio(1);                                       \
      _Pragma("unroll") for (int c = 0; c < 7; ++c) {                      \
        acc[c] = MFMA(Fh[kc], wq[bsel][2 * c], acc[c]);                    \
        acc[c] = MFMA(Fh[kc], wq[bsel][2 * c + 1], acc[c]);                \
        acc[c] = MFMA(Fl[kc], wq[bsel][2 * c], acc[c]);                    \
      }                                                                    \
      __builtin_amdgcn_s_setprio(0);                                       \
    }                                                                      \
  }

  auto wbrelu = [&](const float* bias) {
    const int col_l = lane & 15;
    const int rloc0 = lrbase + (lane >> 4) * 4;
    #pragma unroll
    for (int ct = 0; ct < 7; ++ct) {
      int k = ct * 16 + col_l;
      float b = bias[k];
      #pragma unroll
      for (int j = 0; j < 4; ++j) {
        int row = rloc0 + j;
        float v = fmaxf(acc[ct][j] + b, 0.f);
        unsigned short h16 = f2bf(v);
        unsigned short l16 = f2bf(v - bf2f(h16));
        int byte = row * 256 + ((k * 2) ^ ((row & 7) << 4));
        *(short*)(ldsH + byte) = (short)h16;
        *(short*)(ldsL + byte) = (short)l16;
      }
    }
  };
  auto ldfrags = [&]() {
    #pragma unroll
    for (int kc = 0; kc < 4; ++kc) {
      int r = lrbase + a_r;
      int byte = r * 256 + ((((kc * 4 + a_kg) * 16)) ^ ((r & 7) << 4));
      Fh[kc] = *(const short8*)(ldsH + byte);
      Fl[kc] = *(const short8*)(ldsL + byte);
    }
  };

  MLP_LAYER(W1f);
  wbrelu(b1);
  ldfrags();
  MLP_LAYER(W2f);
  wbrelu(b2);
  ldfrags();
  MLP_LAYER(W3f);

  // epilogue: linear + bias -> t1 (fp32)
  const int col_l = lane & 15;
  const int r0 = row0 + (lane >> 4) * 4;
  #pragma unroll
  for (int ct = 0; ct < 7; ++ct) {
    const int c = ct * 16 + col_l;
    const float b = b3[c];
    #pragma unroll
    for (int j = 0; j < 4; ++j) {
      const int r = r0 + j;
      if (r < N) OUT[(size_t)r * LDP + c] = acc[ct][j] + b;
    }
  }
#undef MLP_LAYER
}

// ---------------- fused GRU (counted-vmcnt double-buffered LDS weight staging, 8 waves) ----------------
// 512 threads = 8 waves x 16 rows = 128 rows/block: staging traffic + barrier cost per row
// HALVED vs R14's 4-wave blocks, and at VGPR<=128 TWO 8-wave blocks can be resident per CU
// (16 waves vs 8) giving cross-block phase diversity. Same proven R14 skeleton: raw s_barrier
// + counted vmcnt (never 0 in the loop; __syncthreads would drain DMA — m97/R13 lesson).
// Per-wave vmem ledger uniform: 3 GLOAD16 per stage-half + 8 unconditional epilogue stores
// (slack rows N..N+255 allocated, never feed real output). h_old/biases preloaded & drained
// up front (loads inside the loop would force full drains — in-order vmcnt).
// Waits: ct0 = 3/3; ct1-5 = 11/11 (3 next-half loads + 8 stores); ct6 = 11/8.
// Rows strictly partitioned per wave -> in-place vs update race-free.
__global__ void __launch_bounds__(512, 2)
gru_kernel(const char* __restrict__ aggp, const char* __restrict__ vsp,
           const short* __restrict__ Wbase,
           const float* __restrict__ br, const float* __restrict__ bz,
           const float* __restrict__ big, const float* __restrict__ bhg,
           char* __restrict__ outp, int N) {
  __shared__ __align__(16) char wlds[49152];  // buf0 @0, buf1 @24576
  const int lane = threadIdx.x & 63, wave = threadIdx.x >> 6;  // 8 waves
  const int row0 = blockIdx.x * 128 + wave * 16;
  const int a_r = lane & 15;
  const int kgo = (lane >> 4) << 4;
  const int col_l = lane & 15;
  const int jr0 = row0 + (lane >> 4) * 4;

  // ---- preloads (all drained before the pipeline starts) ----
  short8 Ah[4], Al[4], Vh[4], Vl[4];
  {
    const char* arow = aggp + (((size_t)(row0 + a_r)) << 9) + kgo;
    const char* vrow = vsp  + (((size_t)(row0 + a_r)) << 9) + kgo;
    #pragma unroll
    for (int kc = 0; kc < 4; ++kc) {
      Ah[kc] = *(const short8*)(arow + kc * 64);
      Al[kc] = *(const short8*)(arow + 256 + kc * 64);
      Vh[kc] = *(const short8*)(vrow + kc * 64);
      Vl[kc] = *(const short8*)(vrow + 256 + kc * 64);
    }
  }
  float ho[7][4];
  #pragma unroll
  for (int ct = 0; ct < 7; ++ct) {
    const int ccol = ct * 16 + col_l;
    #pragma unroll
    for (int j = 0; j < 4; ++j) {
      const char* hrow = vsp + ((size_t)(jr0 + j) << 9);
      ho[ct][j] = bf2f(*(const unsigned short*)(hrow + 2 * ccol)) +
                  bf2f(*(const unsigned short*)(hrow + 256 + 2 * ccol));
    }
  }
  float bR[7], bZ[7], bI[7], bH[7];
  #pragma unroll
  for (int ct = 0; ct < 7; ++ct) {
    const int ccol = ct * 16 + col_l;
    bR[ct] = br[ccol]; bZ[ct] = bz[ccol]; bI[ct] = big[ccol]; bH[ct] = bhg[ccol];
  }
  asm volatile("s_waitcnt vmcnt(0)" ::: "memory");

// wave stages 3 of the 24 chunks of half KH of slice CT into buffer at BOFF
#define GRU_STAGE(CT, KH, BOFF)                                                \
  {                                                                            \
    _Pragma("unroll") for (int q = 0; q < 3; ++q) {                            \
      const int c_ = wave * 3 + q;                                             \
      const int m_ = c_ >> 2, kcl_ = (c_ >> 1) & 1, p_ = c_ & 1;               \
      const size_t gb_ = (size_t)m_ * 65536 +                                  \
          (size_t)(((((KH) * 2 + kcl_) * 8 + (CT)) * 2048) + p_ * 1024);       \
      GLOAD16((const char*)Wbase + gb_ + lane * 16, wlds + (BOFF) + c_ * 1024);\
    }                                                                          \
  }

#define GRU_HALF(KH, BOFF)                                                     \
  {                                                                            \
    _Pragma("unroll") for (int kcl = 0; kcl < 2; ++kcl) {                      \
      const int kc_ = (KH) * 2 + kcl;                                          \
      short8 wt[12];                                                           \
      _Pragma("unroll") for (int mp = 0; mp < 12; ++mp) {                      \
        const int m_ = mp >> 1, p_ = mp & 1;                                   \
        const int chunk_ = m_ * 4 + kcl * 2 + p_;                              \
        wt[mp] = *(const short8*)(wlds + (BOFF) + chunk_ * 1024 + lane * 16);  \
      }                                                                        \
      __builtin_amdgcn_s_setprio(1);                                           \
      rc = MFMA(Ah[kc_], wt[0], rc);  rc = MFMA(Ah[kc_], wt[1], rc);  rc = MFMA(Al[kc_], wt[0], rc); \
      zc = MFMA(Ah[kc_], wt[2], zc);  zc = MFMA(Ah[kc_], wt[3], zc);  zc = MFMA(Al[kc_], wt[2], zc); \
      ic = MFMA(Ah[kc_], wt[4], ic);  ic = MFMA(Ah[kc_], wt[5], ic);  ic = MFMA(Al[kc_], wt[4], ic); \
      rc = MFMA(Vh[kc_], wt[6], rc);  rc = MFMA(Vh[kc_], wt[7], rc);  rc = MFMA(Vl[kc_], wt[6], rc); \
      zc = MFMA(Vh[kc_], wt[8], zc);  zc = MFMA(Vh[kc_], wt[9], zc);  zc = MFMA(Vl[kc_], wt[8], zc); \
      hc = MFMA(Vh[kc_], wt[10], hc); hc = MFMA(Vh[kc_], wt[11], hc); hc = MFMA(Vl[kc_], wt[10], hc); \
      __builtin_amdgcn_s_setprio(0);                                           \
    }                                                                          \
  }

#define GRU_ITER(CT, VA, VB, STG)                                              \
  {                                                                            \
    floatx4 rc = {0.f, 0.f, 0.f, 0.f};                                         \
    floatx4 zc = {0.f, 0.f, 0.f, 0.f};                                         \
    floatx4 ic = {0.f, 0.f, 0.f, 0.f};                                         \
    floatx4 hc = {0.f, 0.f, 0.f, 0.f};                                         \
    asm volatile("s_waitcnt vmcnt(" VA ")" ::: "memory");                      \
    __builtin_amdgcn_s_barrier();                                              \
    GRU_HALF(0, 0)                                                             \
    __builtin_amdgcn_sched_barrier(0);                                         \
    __builtin_amdgcn_s_barrier();                                              \
    if (STG) GRU_STAGE((CT) + 1, 0, 0)                                         \
    asm volatile("s_waitcnt vmcnt(" VB ")" ::: "memory");                      \
    __builtin_amdgcn_s_barrier();                                              \
    GRU_HALF(1, 24576)                                                         \
    __builtin_amdgcn_sched_barrier(0);                                         \
    __builtin_amdgcn_s_barrier();                                              \
    if (STG) GRU_STAGE((CT) + 1, 1, 24576)                                     \
    const float brv = bR[CT], bzv = bZ[CT], bigv = bI[CT], bhgv = bH[CT];      \
    const int ccol = (CT) * 16 + col_l;                                        \
    _Pragma("unroll") for (int j = 0; j < 4; ++j) {                            \
      const float rv = sigmf(rc[j] + brv);                                     \
      const float zv = sigmf(zc[j] + bzv);                                     \
      const float gv = tanhf(ic[j] + bigv + rv * (hc[j] + bhgv));              \
      const float v = (1.f - zv) * gv + zv * ho[CT][j];                        \
      const unsigned short hi = f2bf(v);                                       \
      const unsigned short lo = f2bf(v - bf2f(hi));                            \
      char* orow = outp + ((size_t)(jr0 + j) << 9);                            \
      *(unsigned short*)(orow + 2 * ccol)       = hi;                          \
      *(unsigned short*)(orow + 256 + 2 * ccol) = lo;                          \
    }                                                                          \
  }

  // prologue: both halves of ct=0 in flight (6 outstanding)
  GRU_STAGE(0, 0, 0)
  GRU_STAGE(0, 1, 24576)

  GRU_ITER(0, "3",  "3",  1)
  GRU_ITER(1, "11", "11", 1)
  GRU_ITER(2, "11", "11", 1)
  GRU_ITER(3, "11", "11", 1)
  GRU_ITER(4, "11", "11", 1)
  GRU_ITER(5, "11", "11", 1)
  GRU_ITER(6, "11", "8",  0)

#undef GRU_STAGE
#undef GRU_HALF
#undef GRU_ITER
}

// ---------------- final projection ----------------
__global__ void final_kernel(const char* __restrict__ vsp, const int* __restrict__ sv,
                             const float* __restrict__ pw1, const float* __restrict__ pb1,
                             const float* __restrict__ pw2, const float* __restrict__ pb2,
                             float* __restrict__ out, int SVn) {
  int b = blockIdx.x;
  if (b >= SVn) return;
  int tid = threadIdx.x;  // 64
  int node = sv[b];
  const char* rowp = vsp + ((size_t)node << 9);
  float p = 0.f;
  if (tid < CHS) {
    float acc = 0.f;
    for (int k = 0; k < VHS; ++k) {
      float xv = bf2f(*(const unsigned short*)(rowp + 2 * k)) +
                 bf2f(*(const unsigned short*)(rowp + 256 + 2 * k));
      acc += xv * pw1[k * CHS + tid];
    }
    float h = fmaxf(acc + pb1[tid], 0.f);
    p = h * pw2[tid];
  }
  #pragma unroll
  for (int off = 32; off > 0; off >>= 1) p += __shfl_down(p, off);
  if (tid == 0) out[b] = p + pb2[0];
}

// ---------------- launcher ----------------
extern "C" void kernel_launch(void* const* d_in, const int* in_sizes, int n_in,
                              void* d_out, int out_size, void* d_ws, size_t ws_size,
                              hipStream_t stream) {
  const float* x      = (const float*)d_in[0];
  const int*   ei     = (const int*)d_in[1];
  const int*   sv     = (const int*)d_in[2];
  const float* ind    = (const float*)d_in[3];
  const float* outd   = (const float*)d_in[4];
  const float* tv     = (const float*)d_in[7];
  const float* fm_w1  = (const float*)d_in[8];
  const float* fm_b1  = (const float*)d_in[9];
  const float* fm_w2  = (const float*)d_in[10];
  const float* fm_b2  = (const float*)d_in[11];
  const float* fm_w3  = (const float*)d_in[12];
  const float* fm_b3  = (const float*)d_in[13];
  const float* bm_w1  = (const float*)d_in[14];
  const float* bm_b1  = (const float*)d_in[15];
  const float* bm_w2  = (const float*)d_in[16];
  const float* bm_b2  = (const float*)d_in[17];
  const float* bm_w3  = (const float*)d_in[18];
  const float* bm_b3  = (const float*)d_in[19];
  const float* fg_wih = (const float*)d_in[20];
  const float* fg_whh = (const float*)d_in[21];
  const float* fg_bih = (const float*)d_in[22];
  const float* fg_bhh = (const float*)d_in[23];
  const float* bg_wih = (const float*)d_in[24];
  const float* bg_whh = (const float*)d_in[25];
  const float* bg_bih = (const float*)d_in[26];
  const float* bg_bhh = (const float*)d_in[27];
  const float* pw1    = (const float*)d_in[28];
  const float* pb1    = (const float*)d_in[29];
  const float* pw2    = (const float*)d_in[30];
  const float* pb2    = (const float*)d_in[31];

  const int N   = in_sizes[3];
  const int E   = in_sizes[1] / 2;
  const int SVn = in_sizes[2];

  char* wsb = (char*)d_ws;
  const size_t NP = (size_t)N * LDP;
  float* t1     = (float*)wsb;                           // N*112 fp32
  char*  vs_sp  = wsb + NP * 4;                          // (N+256) split rows
  char*  agg_sp = vs_sp + (size_t)(N + 256) * 512;       // (N+256) split rows
  float* inv_ind  = (float*)(agg_sp + (size_t)(N + 256) * 512);
  float* inv_outd = inv_ind + N;
  short* wfrag    = (short*)(inv_outd + N);
  float* biasbase = (float*)(wfrag + 18 * WFRAG_SZ);
  int* ip      = (int*)(biasbase + 14 * CTW);
  int* rp_in   = ip; ip += N + 1;
  int* rp_out  = ip; ip += N + 1;
  int* col_in  = ip; ip += E;
  int* col_out = ip; ip += E;
  int* cnt     = ip; ip += N;
  int* hin     = ip; ip += N;
  int* hout    = ip; ip += N;
  int* mid     = ip; ip += N;
  int* sums    = ip; ip += 512;

  const size_t need_bytes = (size_t)((char*)(ip) - (char*)d_ws);
  if (ws_size < need_bytes) return;

  auto wf  = [&](int i) { return wfrag + (size_t)i * WFRAG_SZ; };
  auto bia = [&](int i) { return biasbase + (size_t)i * CTW; };

  // --- weights -> fragment-ordered split bf16 ---
  wfrag_kernel<<<8, 256, 0, stream>>>(fm_w1, VHS, 0, wf(0));
  wfrag_kernel<<<8, 256, 0, stream>>>(fm_w2, VHS, 0, wf(1));
  wfrag_kernel<<<8, 256, 0, stream>>>(fm_w3, VHS, 0, wf(2));
  wfrag_kernel<<<8, 256, 0, stream>>>(bm_w1, VHS, 0, wf(3));
  wfrag_kernel<<<8, 256, 0, stream>>>(bm_w2, VHS, 0, wf(4));
  wfrag_kernel<<<8, 256, 0, stream>>>(bm_w3, VHS, 0, wf(5));
  // GRU weights contiguous per direction: fwd = wf(6..11) {Wr,Wz,Wg,Ur,Uz,Ug}, bwd = wf(12..17)
  for (int g = 0; g < 3; ++g) {
    wfrag_kernel<<<8, 256, 0, stream>>>(fg_wih, 3 * VHS, g * VHS, wf(6 + g));
    wfrag_kernel<<<8, 256, 0, stream>>>(fg_whh, 3 * VHS, g * VHS, wf(9 + g));
    wfrag_kernel<<<8, 256, 0, stream>>>(bg_wih, 3 * VHS, g * VHS, wf(12 + g));
    wfrag_kernel<<<8, 256, 0, stream>>>(bg_whh, 3 * VHS, g * VHS, wf(15 + g));
  }
  pad_b_kernel<<<1, 128, 0, stream>>>(fm_b1, 0, nullptr, 0, bia(0));
  pad_b_kernel<<<1, 128, 0, stream>>>(fm_b2, 0, nullptr, 0, bia(1));
  pad_b_kernel<<<1, 128, 0, stream>>>(fm_b3, 0, nullptr, 0, bia(2));
  pad_b_kernel<<<1, 128, 0, stream>>>(bm_b1, 0, nullptr, 0, bia(3));
  pad_b_kernel<<<1, 128, 0, stream>>>(bm_b2, 0, nullptr, 0, bia(4));
  pad_b_kernel<<<1, 128, 0, stream>>>(bm_b3, 0, nullptr, 0, bia(5));
  pad_b_kernel<<<1, 128, 0, stream>>>(fg_bih, 0,       fg_bhh, 0,       bia(6));   // r sum
  pad_b_kernel<<<1, 128, 0, stream>>>(fg_bih, VHS,     fg_bhh, VHS,     bia(7));   // z sum
  pad_b_kernel<<<1, 128, 0, stream>>>(fg_bih, 2 * VHS, nullptr, 0,      bia(8));   // ig
  pad_b_kernel<<<1, 128, 0, stream>>>(fg_bhh, 2 * VHS, nullptr, 0,      bia(9));   // hg
  pad_b_kernel<<<1, 128, 0, stream>>>(bg_bih, 0,       bg_bhh, 0,       bia(10));
  pad_b_kernel<<<1, 128, 0, stream>>>(bg_bih, VHS,     bg_bhh, VHS,     bia(11));
  pad_b_kernel<<<1, 128, 0, stream>>>(bg_bih, 2 * VHS, nullptr, 0,      bia(12));
  pad_b_kernel<<<1, 128, 0, stream>>>(bg_bhh, 2 * VHS, nullptr, 0,      bia(13));

  inv_kernel<<<(N + 255) / 256, 256, 0, stream>>>(ind, outd, inv_ind, inv_outd, N);
  init_vs_kernel<<<N, 128, 0, stream>>>(x, tv, vs_sp, N);

  // --- CSR build (deterministic via per-row sort) ---
  zero_int_kernel<<<(2 * N + 255) / 256, 256, 0, stream>>>(hin, 2 * N);
  hist_kernel<<<(E + 255) / 256, 256, 0, stream>>>(ei, E, hin, hout);
  const int nb = (N + 1023) / 1024;
  scan_block_kernel<<<nb, 256, 0, stream>>>(hin, mid, sums, N);
  scan_sums_kernel<<<1, 256, 0, stream>>>(sums, nb);
  scan_finalize_kernel<<<(N + 255) / 256, 256, 0, stream>>>(mid, sums, rp_in, N);
  scan_block_kernel<<<nb, 256, 0, stream>>>(hout, mid, sums, N);
  scan_sums_kernel<<<1, 256, 0, stream>>>(sums, nb);
  scan_finalize_kernel<<<(N + 255) / 256, 256, 0, stream>>>(mid, sums, rp_out, N);
  zero_int_kernel<<<(N + 255) / 256, 256, 0, stream>>>(cnt, N);
  fill_kernel<<<(E + 255) / 256, 256, 0, stream>>>(ei, E, 0, E, rp_in, cnt, col_in);
  sort_rows_kernel<<<(N + 255) / 256, 256, 0, stream>>>(rp_in, col_in, N);
  zero_int_kernel<<<(N + 255) / 256, 256, 0, stream>>>(cnt, N);
  fill_kernel<<<(E + 255) / 256, 256, 0, stream>>>(ei, E, E, 0, rp_out, cnt, col_out);
  sort_rows_kernel<<<(N + 255) / 256, 256, 0, stream>>>(rp_out, col_out, N);

  // --- 8 rounds x 2 directions ---
  const int gridMM  = (N + 63) / 64;
  const int gridGRU = (N + 127) / 128;
  const int gridG   = (N + 7) / 8;
  for (int rd = 0; rd < 8; ++rd) {
    for (int dir = 0; dir < 2; ++dir) {
      const int mw = dir ? 3 : 0;
      const int gb = dir ? 10 : 6;   // biases (r,z,ig,hg)
      const int* rp   = dir ? rp_out : rp_in;
      const int* col  = dir ? col_out : col_in;
      const float* iv = dir ? inv_outd : inv_ind;

      // m = MLP(vs) -> t1 (fp32)
      mlp3_kernel<<<gridMM, 256, 0, stream>>>(vs_sp, wf(mw + 0), wf(mw + 1), wf(mw + 2),
                                              bia(mw + 0), bia(mw + 1), bia(mw + 2), t1, N);
      // agg = segsum(t1)/deg -> split-bf16
      gather_kernel<<<gridG, 256, 0, stream>>>(t1, rp, col, iv, agg_sp, N);
      // vs = GRU(agg, vs), in place; weight base = 6 contiguous fragment matrices
      gru_kernel<<<gridGRU, 512, 0, stream>>>(agg_sp, vs_sp, wf(dir ? 12 : 6),
                                              bia(gb + 0), bia(gb + 1), bia(gb + 2), bia(gb + 3),
                                              vs_sp, N);
    }
  }

  final_kernel<<<SVn, 64, 0, stream>>>(vs_sp, sv, pw1, pb1, pw2, pb2, (float*)d_out, SVn);
}

// Round 16
// 2867.661 us; speedup vs baseline: 1.2066x; 1.2066x over previous
//
#include <hip/hip_runtime.h>
#include <math.h>

#define NVTC 7
#define VHS 100
#define CHS 30
#define LDP 112         // t1 (fp32) row stride
#define CTW 128         // padded bias length
#define WFRAG_SZ 32768  // shorts per fragment-ordered weight matrix (hi+lo)
// split-bf16 activation row: 512 B = 128 bf16-hi shorts + 128 bf16-lo shorts (cols 100..127 zero)

typedef short short8 __attribute__((ext_vector_type(8)));
typedef float floatx4 __attribute__((ext_vector_type(4)));

#define MFMA(a, b, c) __builtin_amdgcn_mfma_f32_16x16x32_bf16((a), (b), (c), 0, 0, 0)

// async global->LDS DMA, 16B/lane; LDS dest must be wave-uniform base (+ lane*16 implicit)
#define GLOAD16(g, l)                                                              \
  __builtin_amdgcn_global_load_lds((const __attribute__((address_space(1))) void*)(g), \
                                   (__attribute__((address_space(3))) void*)(l), 16, 0, 0)

__device__ __forceinline__ unsigned short f2bf(float f) {
  unsigned u = __float_as_uint(f);
  return (unsigned short)((u + 0x7fffu + ((u >> 16) & 1u)) >> 16);
}
__device__ __forceinline__ float bf2f(unsigned short h) {
  return __uint_as_float((unsigned)h << 16);
}
__device__ __forceinline__ float sigmf(float v) { return 1.f / (1.f + expf(-v)); }

// ---------------- utility kernels ----------------

__global__ void zero_int_kernel(int* __restrict__ p, int n) {
  int i = blockIdx.x * 256 + threadIdx.x;
  if (i < n) p[i] = 0;
}

__global__ void inv_kernel(const float* __restrict__ ind, const float* __restrict__ outd,
                           float* __restrict__ inv_ind, float* __restrict__ inv_outd, int n) {
  int i = blockIdx.x * 256 + threadIdx.x;
  if (i < n) { inv_ind[i] = 1.0f / ind[i]; inv_outd[i] = 1.0f / outd[i]; }
}

// weight -> fragment-ordered split-bf16 (hi plane + lo plane) for 16x16x32 MFMA B-operand
__global__ void wfrag_kernel(const float* __restrict__ src, int srcLD, int colOff,
                             short* __restrict__ dst) {
  int t = blockIdx.x * 256 + threadIdx.x;
  if (t >= 2048) return;
  int lane = t & 63, rest = t >> 6;
  int ct = rest & 7, kc = rest >> 3;
  int col = ct * 16 + (lane & 15);
  int kbase = kc * 32 + (lane >> 4) * 8;
  short8 hv, lv;
  #pragma unroll
  for (int i = 0; i < 8; ++i) {
    int k = kbase + i;
    float v = (k < VHS && col < VHS) ? src[(size_t)k * srcLD + colOff + col] : 0.f;
    unsigned short h16 = f2bf(v);
    hv[i] = (short)h16;
    lv[i] = (short)f2bf(v - bf2f(h16));
  }
  int base = ((kc * 8 + ct) * 2 * 64 + lane) * 8;
  *(short8*)(dst + base)       = hv;
  *(short8*)(dst + base + 512) = lv;
}

__global__ void pad_b_kernel(const float* __restrict__ b1, int off1,
                             const float* b2, int off2, float* __restrict__ dst) {
  int c = threadIdx.x;  // 128 threads
  float v = 0.f;
  if (c < VHS) { v = b1[off1 + c]; if (b2) v += b2[off2 + c]; }
  dst[c] = v;
}

// vs0 = x @ type_vec, written in split-bf16 row format (cols >= 100 zero)
__global__ void init_vs_kernel(const float* __restrict__ x, const float* __restrict__ tv,
                               char* __restrict__ vsp, int N) {
  int node = blockIdx.x, c = threadIdx.x;  // 128 threads
  if (node >= N) return;
  float v = 0.f;
  if (c < VHS) {
    #pragma unroll
    for (int t = 0; t < NVTC; ++t) v += x[(size_t)node * NVTC + t] * tv[t * VHS + c];
  }
  unsigned short hi = f2bf(v);
  unsigned short lo = f2bf(v - bf2f(hi));
  char* rowp = vsp + ((size_t)node << 9);
  *(unsigned short*)(rowp + 2 * c)       = hi;
  *(unsigned short*)(rowp + 256 + 2 * c) = lo;
}

// ---------------- CSR build (deterministic) ----------------

__global__ void hist_kernel(const int* __restrict__ ei, int E, int* hin, int* hout) {
  int e = blockIdx.x * 256 + threadIdx.x;
  if (e < E) {
    atomicAdd(&hout[ei[e]], 1);
    atomicAdd(&hin[ei[E + e]], 1);
  }
}

__global__ void scan_block_kernel(const int* __restrict__ in, int* __restrict__ mid,
                                  int* __restrict__ sums, int n) {
  __shared__ int lds[256];
  int tid = threadIdx.x;
  int base = blockIdx.x * 1024 + tid * 4;
  int v0 = (base + 0 < n) ? in[base + 0] : 0;
  int v1 = (base + 1 < n) ? in[base + 1] : 0;
  int v2 = (base + 2 < n) ? in[base + 2] : 0;
  int v3 = (base + 3 < n) ? in[base + 3] : 0;
  int s = v0 + v1 + v2 + v3;
  lds[tid] = s;
  __syncthreads();
  for (int off = 1; off < 256; off <<= 1) {
    int t = (tid >= off) ? lds[tid - off] : 0;
    __syncthreads();
    lds[tid] += t;
    __syncthreads();
  }
  int excl = lds[tid] - s;
  int e0 = excl + v0, e1 = e0 + v1, e2 = e1 + v2, e3 = e2 + v3;
  if (base + 0 < n) mid[base + 0] = e0;
  if (base + 1 < n) mid[base + 1] = e1;
  if (base + 2 < n) mid[base + 2] = e2;
  if (base + 3 < n) mid[base + 3] = e3;
  if (tid == 255) sums[blockIdx.x] = lds[255];
}

__global__ void scan_sums_kernel(int* sums, int nb) {
  __shared__ int lds[256];
  int tid = threadIdx.x;
  int v = (tid < nb) ? sums[tid] : 0;
  lds[tid] = v;
  __syncthreads();
  for (int off = 1; off < 256; off <<= 1) {
    int t = (tid >= off) ? lds[tid - off] : 0;
    __syncthreads();
    lds[tid] += t;
    __syncthreads();
  }
  if (tid < nb) sums[tid] = lds[tid];
}

__global__ void scan_finalize_kernel(const int* __restrict__ mid, const int* __restrict__ sums,
                                     int* __restrict__ rp, int n) {
  int i = blockIdx.x * 256 + threadIdx.x;
  if (i >= n) return;
  int blk = i >> 10;
  int add = (blk > 0) ? sums[blk - 1] : 0;
  rp[i + 1] = mid[i] + add;
  if (i == 0) rp[0] = 0;
}

__global__ void fill_kernel(const int* __restrict__ ei, int E, int gOff, int sOff,
                            const int* __restrict__ rp, int* cnt, int* col) {
  int e = blockIdx.x * 256 + threadIdx.x;
  if (e >= E) return;
  int v = ei[sOff + e];
  int p = rp[v] + atomicAdd(&cnt[v], 1);
  col[p] = ei[gOff + e];
}

__global__ void sort_rows_kernel(const int* __restrict__ rp, int* col, int n) {
  int v = blockIdx.x * 256 + threadIdx.x;
  if (v >= n) return;
  int a = rp[v], b = rp[v + 1];
  for (int i = a + 1; i < b; ++i) {
    int key = col[i];
    int j = i - 1;
    while (j >= a && col[j] > key) { col[j + 1] = col[j]; --j; }
    col[j + 1] = key;
  }
}

// agg[v] = (sum of m[u] over sorted neighbors) * iv[v], written split-bf16.
__global__ void __launch_bounds__(256)
gather_kernel(const float* __restrict__ m, const int* __restrict__ rp,
              const int* __restrict__ col, const float* __restrict__ iv,
              char* __restrict__ aggp, int N) {
  int v = blockIdx.x * 8 + (threadIdx.x >> 5);
  if (v >= N) return;
  int lane = threadIdx.x & 31;
  char* rowp = aggp + ((size_t)v << 9);
  if (lane < 28) {
    float4 a = make_float4(0.f, 0.f, 0.f, 0.f);
    int s = rp[v], e = rp[v + 1];
    for (int i = s; i < e; ++i) {
      float4 u = ((const float4*)(m + (size_t)col[i] * LDP))[lane];
      a.x += u.x; a.y += u.y; a.z += u.z; a.w += u.w;
    }
    const float sc = iv[v];
    a.x *= sc; a.y *= sc; a.z *= sc; a.w *= sc;
    unsigned short h0 = f2bf(a.x), h1 = f2bf(a.y), h2 = f2bf(a.z), h3 = f2bf(a.w);
    unsigned short l0 = f2bf(a.x - bf2f(h0)), l1 = f2bf(a.y - bf2f(h1));
    unsigned short l2 = f2bf(a.z - bf2f(h2)), l3 = f2bf(a.w - bf2f(h3));
    *(uint2*)(rowp + 8 * lane) =
        make_uint2((unsigned)h0 | ((unsigned)h1 << 16), (unsigned)h2 | ((unsigned)h3 << 16));
    *(uint2*)(rowp + 256 + 8 * lane) =
        make_uint2((unsigned)l0 | ((unsigned)l1 << 16), (unsigned)l2 | ((unsigned)l3 << 16));
  } else {
    *(uint2*)(rowp + 8 * lane)       = make_uint2(0u, 0u);
    *(uint2*)(rowp + 256 + 8 * lane) = make_uint2(0u, 0u);
  }
}

// ---------------- fused MLP (counted-vmcnt LDS weight staging, 4 waves) ----------------
// 256 threads = 4 waves x 16 rows. Per (layer,kc) the 16KB weight kc-slice is DMA-staged
// into one of two STATIC 16KB LDS buffers (4 chunks/wave), double-buffered across the 12
// slices (3 layers x 4 kc) with raw s_barrier + counted vmcnt(4) (never 0 until the last
// slice) — same proven R14 gru skeleton. Per-block weight traffic 768KB -> 192KB.
// Biases preloaded to registers so the in-loop vmem ledger is exactly 4 loads/stage/wave.
// LDS: handoff hi/lo 32KB @0/@16384, weight buffers WA @32768, WB @49152 (64KB total).
// No early return (barriers); frag loads use allocated slack rows; epilogue stores guarded
// (they sit after the final vmcnt wait, so the ledger is unaffected).
__global__ void __launch_bounds__(256, 2)
mlp3_kernel(const char* __restrict__ vsp,
            const short* __restrict__ W1f, const short* __restrict__ W2f,
            const short* __restrict__ W3f,
            const float* __restrict__ b1, const float* __restrict__ b2,
            const float* __restrict__ b3, float* __restrict__ OUT, int N) {
  __shared__ __align__(16) char lds[65536];
  char* ldsH = lds;
  char* ldsL = lds + 16384;
  const int lane = threadIdx.x & 63, wave = threadIdx.x >> 6;
  const int lrbase = wave * 16;
  const int row0 = blockIdx.x * 64 + lrbase;
  const int a_r = lane & 15, a_kg = lane >> 4;
  const int col_l = lane & 15;

  // ---- preloads (drained before the pipeline) ----
  short8 Fh[4], Fl[4];
  {
    const char* vrow = vsp + (((size_t)(row0 + a_r)) << 9) + (a_kg << 4);
    #pragma unroll
    for (int kc = 0; kc < 4; ++kc) {
      Fh[kc] = *(const short8*)(vrow + kc * 64);
      Fl[kc] = *(const short8*)(vrow + 256 + kc * 64);
    }
  }
  float B1[7], B2[7], B3[7];
  #pragma unroll
  for (int ct = 0; ct < 7; ++ct) {
    const int k = ct * 16 + col_l;
    B1[ct] = b1[k]; B2[ct] = b2[k]; B3[ct] = b3[k];
  }
  // zero pad handoff slots k=112..127 for this wave's 16 rows (LDS only)
  if (lane < 32) {
    int row = lrbase + (lane >> 1), sl = 14 + (lane & 1);
    int byte = row * 256 + ((sl * 16) ^ ((row & 7) << 4));
    short8 z = {0, 0, 0, 0, 0, 0, 0, 0};
    *(short8*)(ldsH + byte) = z;
    *(short8*)(ldsL + byte) = z;
  }
  asm volatile("s_waitcnt vmcnt(0)" ::: "memory");

  floatx4 acc[7];
  #pragma unroll
  for (int c = 0; c < 7; ++c) acc[c] = (floatx4){0.f, 0.f, 0.f, 0.f};

// stage kc-slice KC of weight matrix WF into LDS buffer at BOFF (4 chunks/wave)
#define MSTAGE(WF, KC, BOFF)                                                   \
  {                                                                            \
    _Pragma("unroll") for (int q = 0; q < 4; ++q) {                            \
      const int c_ = wave * 4 + q;                                             \
      GLOAD16((const char*)(WF) + (size_t)((KC) * 16384 + c_ * 1024) + lane * 16, \
              lds + (BOFF) + c_ * 1024);                                       \
    }                                                                          \
  }

// wait + consume one kc-slice: 21 MFMAs over 7 cts (order identical to prior rounds)
#define MCOMP(KC, BOFF, VA)                                                    \
  {                                                                            \
    asm volatile("s_waitcnt vmcnt(" VA ")" ::: "memory");                      \
    __builtin_amdgcn_s_barrier();                                              \
    short8 wt[14];                                                             \
    _Pragma("unroll") for (int c = 0; c < 7; ++c) {                            \
      wt[2 * c]     = *(const short8*)(lds + (BOFF) + (2 * c) * 1024 + lane * 16); \
      wt[2 * c + 1] = *(const short8*)(lds + (BOFF) + (2 * c + 1) * 1024 + lane * 16); \
    }                                                                          \
    __builtin_amdgcn_s_setprio(1);                                             \
    _Pragma("unroll") for (int c = 0; c < 7; ++c) {                            \
      acc[c] = MFMA(Fh[KC], wt[2 * c], acc[c]);                                \
      acc[c] = MFMA(Fh[KC], wt[2 * c + 1], acc[c]);                            \
      acc[c] = MFMA(Fl[KC], wt[2 * c], acc[c]);                                \
    }                                                                          \
    __builtin_amdgcn_s_setprio(0);                                             \
    __builtin_amdgcn_sched_barrier(0);                                         \
    __builtin_amdgcn_s_barrier();                                              \
  }

  auto wbrelu = [&](const float* B) {
    const int rloc0 = lrbase + (lane >> 4) * 4;
    #pragma unroll
    for (int ct = 0; ct < 7; ++ct) {
      int k = ct * 16 + col_l;
      #pragma unroll
      for (int j = 0; j < 4; ++j) {
        int row = rloc0 + j;
        float v = fmaxf(acc[ct][j] + B[ct], 0.f);
        unsigned short h16 = f2bf(v);
        unsigned short l16 = f2bf(v - bf2f(h16));
        int byte = row * 256 + ((k * 2) ^ ((row & 7) << 4));
        *(short*)(ldsH + byte) = (short)h16;
        *(short*)(ldsL + byte) = (short)l16;
      }
      acc[ct] = (floatx4){0.f, 0.f, 0.f, 0.f};
    }
  };
  auto ldfrags = [&]() {
    #pragma unroll
    for (int kc = 0; kc < 4; ++kc) {
      int r = lrbase + a_r;
      int byte = r * 256 + ((((kc * 4 + a_kg) * 16)) ^ ((r & 7) << 4));
      Fh[kc] = *(const short8*)(ldsH + byte);
      Fl[kc] = *(const short8*)(ldsL + byte);
    }
  };

  // 12-slice static pipeline; WA @32768, WB @49152
  MSTAGE(W1f, 0, 32768) MSTAGE(W1f, 1, 49152)
  MCOMP(0, 32768, "4")  MSTAGE(W1f, 2, 32768)
  MCOMP(1, 49152, "4")  MSTAGE(W1f, 3, 49152)
  MCOMP(2, 32768, "4")  MSTAGE(W2f, 0, 32768)
  MCOMP(3, 49152, "4")  MSTAGE(W2f, 1, 49152)
  wbrelu(B1); ldfrags();
  MCOMP(0, 32768, "4")  MSTAGE(W2f, 2, 32768)
  MCOMP(1, 49152, "4")  MSTAGE(W2f, 3, 49152)
  MCOMP(2, 32768, "4")  MSTAGE(W3f, 0, 32768)
  MCOMP(3, 49152, "4")  MSTAGE(W3f, 1, 49152)
  wbrelu(B2); ldfrags();
  MCOMP(0, 32768, "4")  MSTAGE(W3f, 2, 32768)
  MCOMP(1, 49152, "4")  MSTAGE(W3f, 3, 49152)
  MCOMP(2, 32768, "4")
  MCOMP(3, 49152, "0")

  // epilogue: linear + bias -> t1 (fp32); after final wait, guards are ledger-safe
  const int r0 = row0 + (lane >> 4) * 4;
  #pragma unroll
  for (int ct = 0; ct < 7; ++ct) {
    const int c = ct * 16 + col_l;
    #pragma unroll
    for (int j = 0; j < 4; ++j) {
      const int r = r0 + j;
      if (r < N) OUT[(size_t)r * LDP + c] = acc[ct][j] + B3[ct];
    }
  }
#undef MSTAGE
#undef MCOMP
}

// ---------------- fused GRU (counted-vmcnt double-buffered LDS weight staging) ----------------
// R14 proven version: 256 threads = 4 waves x 16 rows; raw s_barrier + counted vmcnt.
// Waits: ct0 = 6/6; ct1-5 = 14/14 (6 next-half loads + 8 stores); ct6 = 14/8.
__global__ void __launch_bounds__(256, 2)
gru_kernel(const char* __restrict__ aggp, const char* __restrict__ vsp,
           const short* __restrict__ Wbase,
           const float* __restrict__ br, const float* __restrict__ bz,
           const float* __restrict__ big, const float* __restrict__ bhg,
           char* __restrict__ outp, int N) {
  __shared__ __align__(16) char wlds[49152];  // buf0 @0, buf1 @24576
  const int lane = threadIdx.x & 63, wave = threadIdx.x >> 6;
  const int row0 = blockIdx.x * 64 + wave * 16;
  const int a_r = lane & 15;
  const int kgo = (lane >> 4) << 4;
  const int col_l = lane & 15;
  const int jr0 = row0 + (lane >> 4) * 4;

  // ---- preloads (all drained before the pipeline starts) ----
  short8 Ah[4], Al[4], Vh[4], Vl[4];
  {
    const char* arow = aggp + (((size_t)(row0 + a_r)) << 9) + kgo;
    const char* vrow = vsp  + (((size_t)(row0 + a_r)) << 9) + kgo;
    #pragma unroll
    for (int kc = 0; kc < 4; ++kc) {
      Ah[kc] = *(const short8*)(arow + kc * 64);
      Al[kc] = *(const short8*)(arow + 256 + kc * 64);
      Vh[kc] = *(const short8*)(vrow + kc * 64);
      Vl[kc] = *(const short8*)(vrow + 256 + kc * 64);
    }
  }
  float ho[7][4];
  #pragma unroll
  for (int ct = 0; ct < 7; ++ct) {
    const int ccol = ct * 16 + col_l;
    #pragma unroll
    for (int j = 0; j < 4; ++j) {
      const char* hrow = vsp + ((size_t)(jr0 + j) << 9);
      ho[ct][j] = bf2f(*(const unsigned short*)(hrow + 2 * ccol)) +
                  bf2f(*(const unsigned short*)(hrow + 256 + 2 * ccol));
    }
  }
  float bR[7], bZ[7], bI[7], bH[7];
  #pragma unroll
  for (int ct = 0; ct < 7; ++ct) {
    const int ccol = ct * 16 + col_l;
    bR[ct] = br[ccol]; bZ[ct] = bz[ccol]; bI[ct] = big[ccol]; bH[ct] = bhg[ccol];
  }
  asm volatile("s_waitcnt vmcnt(0)" ::: "memory");

#define GRU_STAGE(CT, KH, BOFF)                                                \
  {                                                                            \
    _Pragma("unroll") for (int q = 0; q < 6; ++q) {                            \
      const int c_ = wave * 6 + q;                                             \
      const int m_ = c_ >> 2, kcl_ = (c_ >> 1) & 1, p_ = c_ & 1;               \
      const size_t gb_ = (size_t)m_ * 65536 +                                  \
          (size_t)(((((KH) * 2 + kcl_) * 8 + (CT)) * 2048) + p_ * 1024);       \
      GLOAD16((const char*)Wbase + gb_ + lane * 16, wlds + (BOFF) + c_ * 1024);\
    }                                                                          \
  }

#define GRU_HALF(KH, BOFF)                                                     \
  {                                                                            \
    _Pragma("unroll") for (int kcl = 0; kcl < 2; ++kcl) {                      \
      const int kc_ = (KH) * 2 + kcl;                                          \
      short8 wt[12];                                                           \
      _Pragma("unroll") for (int mp = 0; mp < 12; ++mp) {                      \
        const int m_ = mp >> 1, p_ = mp & 1;                                   \
        const int chunk_ = m_ * 4 + kcl * 2 + p_;                              \
        wt[mp] = *(const short8*)(wlds + (BOFF) + chunk_ * 1024 + lane * 16);  \
      }                                                                        \
      __builtin_amdgcn_s_setprio(1);                                           \
      rc = MFMA(Ah[kc_], wt[0], rc);  rc = MFMA(Ah[kc_], wt[1], rc);  rc = MFMA(Al[kc_], wt[0], rc); \
      zc = MFMA(Ah[kc_], wt[2], zc);  zc = MFMA(Ah[kc_], wt[3], zc);  zc = MFMA(Al[kc_], wt[2], zc); \
      ic = MFMA(Ah[kc_], wt[4], ic);  ic = MFMA(Ah[kc_], wt[5], ic);  ic = MFMA(Al[kc_], wt[4], ic); \
      rc = MFMA(Vh[kc_], wt[6], rc);  rc = MFMA(Vh[kc_], wt[7], rc);  rc = MFMA(Vl[kc_], wt[6], rc); \
      zc = MFMA(Vh[kc_], wt[8], zc);  zc = MFMA(Vh[kc_], wt[9], zc);  zc = MFMA(Vl[kc_], wt[8], zc); \
      hc = MFMA(Vh[kc_], wt[10], hc); hc = MFMA(Vh[kc_], wt[11], hc); hc = MFMA(Vl[kc_], wt[10], hc); \
      __builtin_amdgcn_s_setprio(0);                                           \
    }                                                                          \
  }

#define GRU_ITER(CT, VA, VB, STG)                                              \
  {                                                                            \
    floatx4 rc = {0.f, 0.f, 0.f, 0.f};                                         \
    floatx4 zc = {0.f, 0.f, 0.f, 0.f};                                         \
    floatx4 ic = {0.f, 0.f, 0.f, 0.f};                                         \
    floatx4 hc = {0.f, 0.f, 0.f, 0.f};                                         \
    asm volatile("s_waitcnt vmcnt(" VA ")" ::: "memory");                      \
    __builtin_amdgcn_s_barrier();                                              \
    GRU_HALF(0, 0)                                                             \
    __builtin_amdgcn_sched_barrier(0);                                         \
    __builtin_amdgcn_s_barrier();                                              \
    if (STG) GRU_STAGE((CT) + 1, 0, 0)                                         \
    asm volatile("s_waitcnt vmcnt(" VB ")" ::: "memory");                      \
    __builtin_amdgcn_s_barrier();                                              \
    GRU_HALF(1, 24576)                                                         \
    __builtin_amdgcn_sched_barrier(0);                                         \
    __builtin_amdgcn_s_barrier();                                              \
    if (STG) GRU_STAGE((CT) + 1, 1, 24576)                                     \
    const float brv = bR[CT], bzv = bZ[CT], bigv = bI[CT], bhgv = bH[CT];      \
    const int ccol = (CT) * 16 + col_l;                                        \
    _Pragma("unroll") for (int j = 0; j < 4; ++j) {                            \
      const float rv = sigmf(rc[j] + brv);                                     \
      const float zv = sigmf(zc[j] + bzv);                                     \
      const float gv = tanhf(ic[j] + bigv + rv * (hc[j] + bhgv));              \
      const float v = (1.f - zv) * gv + zv * ho[CT][j];                        \
      const unsigned short hi = f2bf(v);                                       \
      const unsigned short lo = f2bf(v - bf2f(hi));                            \
      char* orow = outp + ((size_t)(jr0 + j) << 9);                            \
      *(unsigned short*)(orow + 2 * ccol)       = hi;                          \
      *(unsigned short*)(orow + 256 + 2 * ccol) = lo;                          \
    }                                                                          \
  }

  // prologue: both halves of ct=0 in flight (12 outstanding)
  GRU_STAGE(0, 0, 0)
  GRU_STAGE(0, 1, 24576)

  GRU_ITER(0, "6",  "6",  1)
  GRU_ITER(1, "14", "14", 1)
  GRU_ITER(2, "14", "14", 1)
  GRU_ITER(3, "14", "14", 1)
  GRU_ITER(4, "14", "14", 1)
  GRU_ITER(5, "14", "14", 1)
  GRU_ITER(6, "14", "8",  0)

#undef GRU_STAGE
#undef GRU_HALF
#undef GRU_ITER
}

// ---------------- final projection ----------------
__global__ void final_kernel(const char* __restrict__ vsp, const int* __restrict__ sv,
                             const float* __restrict__ pw1, const float* __restrict__ pb1,
                             const float* __restrict__ pw2, const float* __restrict__ pb2,
                             float* __restrict__ out, int SVn) {
  int b = blockIdx.x;
  if (b >= SVn) return;
  int tid = threadIdx.x;  // 64
  int node = sv[b];
  const char* rowp = vsp + ((size_t)node << 9);
  float p = 0.f;
  if (tid < CHS) {
    float acc = 0.f;
    for (int k = 0; k < VHS; ++k) {
      float xv = bf2f(*(const unsigned short*)(rowp + 2 * k)) +
                 bf2f(*(const unsigned short*)(rowp + 256 + 2 * k));
      acc += xv * pw1[k * CHS + tid];
    }
    float h = fmaxf(acc + pb1[tid], 0.f);
    p = h * pw2[tid];
  }
  #pragma unroll
  for (int off = 32; off > 0; off >>= 1) p += __shfl_down(p, off);
  if (tid == 0) out[b] = p + pb2[0];
}

// ---------------- launcher ----------------
extern "C" void kernel_launch(void* const* d_in, const int* in_sizes, int n_in,
                              void* d_out, int out_size, void* d_ws, size_t ws_size,
                              hipStream_t stream) {
  const float* x      = (const float*)d_in[0];
  const int*   ei     = (const int*)d_in[1];
  const int*   sv     = (const int*)d_in[2];
  const float* ind    = (const float*)d_in[3];
  const float* outd   = (const float*)d_in[4];
  const float* tv     = (const float*)d_in[7];
  const float* fm_w1  = (const float*)d_in[8];
  const float* fm_b1  = (const float*)d_in[9];
  const float* fm_w2  = (const float*)d_in[10];
  const float* fm_b2  = (const float*)d_in[11];
  const float* fm_w3  = (const float*)d_in[12];
  const float* fm_b3  = (const float*)d_in[13];
  const float* bm_w1  = (const float*)d_in[14];
  const float* bm_b1  = (const float*)d_in[15];
  const float* bm_w2  = (const float*)d_in[16];
  const float* bm_b2  = (const float*)d_in[17];
  const float* bm_w3  = (const float*)d_in[18];
  const float* bm_b3  = (const float*)d_in[19];
  const float* fg_wih = (const float*)d_in[20];
  const float* fg_whh = (const float*)d_in[21];
  const float* fg_bih = (const float*)d_in[22];
  const float* fg_bhh = (const float*)d_in[23];
  const float* bg_wih = (const float*)d_in[24];
  const float* bg_whh = (const float*)d_in[25];
  const float* bg_bih = (const float*)d_in[26];
  const float* bg_bhh = (const float*)d_in[27];
  const float* pw1    = (const float*)d_in[28];
  const float* pb1    = (const float*)d_in[29];
  const float* pw2    = (const float*)d_in[30];
  const float* pb2    = (const float*)d_in[31];

  const int N   = in_sizes[3];
  const int E   = in_sizes[1] / 2;
  const int SVn = in_sizes[2];

  char* wsb = (char*)d_ws;
  const size_t NP = (size_t)N * LDP;
  float* t1     = (float*)wsb;                           // N*112 fp32
  char*  vs_sp  = wsb + NP * 4;                          // (N+256) split rows
  char*  agg_sp = vs_sp + (size_t)(N + 256) * 512;       // (N+256) split rows
  float* inv_ind  = (float*)(agg_sp + (size_t)(N + 256) * 512);
  float* inv_outd = inv_ind + N;
  short* wfrag    = (short*)(inv_outd + N);
  float* biasbase = (float*)(wfrag + 18 * WFRAG_SZ);
  int* ip      = (int*)(biasbase + 14 * CTW);
  int* rp_in   = ip; ip += N + 1;
  int* rp_out  = ip; ip += N + 1;
  int* col_in  = ip; ip += E;
  int* col_out = ip; ip += E;
  int* cnt     = ip; ip += N;
  int* hin     = ip; ip += N;
  int* hout    = ip; ip += N;
  int* mid     = ip; ip += N;
  int* sums    = ip; ip += 512;

  const size_t need_bytes = (size_t)((char*)(ip) - (char*)d_ws);
  if (ws_size < need_bytes) return;

  auto wf  = [&](int i) { return wfrag + (size_t)i * WFRAG_SZ; };
  auto bia = [&](int i) { return biasbase + (size_t)i * CTW; };

  // --- weights -> fragment-ordered split bf16 ---
  wfrag_kernel<<<8, 256, 0, stream>>>(fm_w1, VHS, 0, wf(0));
  wfrag_kernel<<<8, 256, 0, stream>>>(fm_w2, VHS, 0, wf(1));
  wfrag_kernel<<<8, 256, 0, stream>>>(fm_w3, VHS, 0, wf(2));
  wfrag_kernel<<<8, 256, 0, stream>>>(bm_w1, VHS, 0, wf(3));
  wfrag_kernel<<<8, 256, 0, stream>>>(bm_w2, VHS, 0, wf(4));
  wfrag_kernel<<<8, 256, 0, stream>>>(bm_w3, VHS, 0, wf(5));
  // GRU weights contiguous per direction: fwd = wf(6..11) {Wr,Wz,Wg,Ur,Uz,Ug}, bwd = wf(12..17)
  for (int g = 0; g < 3; ++g) {
    wfrag_kernel<<<8, 256, 0, stream>>>(fg_wih, 3 * VHS, g * VHS, wf(6 + g));
    wfrag_kernel<<<8, 256, 0, stream>>>(fg_whh, 3 * VHS, g * VHS, wf(9 + g));
    wfrag_kernel<<<8, 256, 0, stream>>>(bg_wih, 3 * VHS, g * VHS, wf(12 + g));
    wfrag_kernel<<<8, 256, 0, stream>>>(bg_whh, 3 * VHS, g * VHS, wf(15 + g));
  }
  pad_b_kernel<<<1, 128, 0, stream>>>(fm_b1, 0, nullptr, 0, bia(0));
  pad_b_kernel<<<1, 128, 0, stream>>>(fm_b2, 0, nullptr, 0, bia(1));
  pad_b_kernel<<<1, 128, 0, stream>>>(fm_b3, 0, nullptr, 0, bia(2));
  pad_b_kernel<<<1, 128, 0, stream>>>(bm_b1, 0, nullptr, 0, bia(3));
  pad_b_kernel<<<1, 128, 0, stream>>>(bm_b2, 0, nullptr, 0, bia(4));
  pad_b_kernel<<<1, 128, 0, stream>>>(bm_b3, 0, nullptr, 0, bia(5));
  pad_b_kernel<<<1, 128, 0, stream>>>(fg_bih, 0,       fg_bhh, 0,       bia(6));   // r sum
  pad_b_kernel<<<1, 128, 0, stream>>>(fg_bih, VHS,     fg_bhh, VHS,     bia(7));   // z sum
  pad_b_kernel<<<1, 128, 0, stream>>>(fg_bih, 2 * VHS, nullptr, 0,      bia(8));   // ig
  pad_b_kernel<<<1, 128, 0, stream>>>(fg_bhh, 2 * VHS, nullptr, 0,      bia(9));   // hg
  pad_b_kernel<<<1, 128, 0, stream>>>(bg_bih, 0,       bg_bhh, 0,       bia(10));
  pad_b_kernel<<<1, 128, 0, stream>>>(bg_bih, VHS,     bg_bhh, VHS,     bia(11));
  pad_b_kernel<<<1, 128, 0, stream>>>(bg_bih, 2 * VHS, nullptr, 0,      bia(12));
  pad_b_kernel<<<1, 128, 0, stream>>>(bg_bhh, 2 * VHS, nullptr, 0,      bia(13));

  inv_kernel<<<(N + 255) / 256, 256, 0, stream>>>(ind, outd, inv_ind, inv_outd, N);
  init_vs_kernel<<<N, 128, 0, stream>>>(x, tv, vs_sp, N);

  // --- CSR build (deterministic via per-row sort) ---
  zero_int_kernel<<<(2 * N + 255) / 256, 256, 0, stream>>>(hin, 2 * N);
  hist_kernel<<<(E + 255) / 256, 256, 0, stream>>>(ei, E, hin, hout);
  const int nb = (N + 1023) / 1024;
  scan_block_kernel<<<nb, 256, 0, stream>>>(hin, mid, sums, N);
  scan_sums_kernel<<<1, 256, 0, stream>>>(sums, nb);
  scan_finalize_kernel<<<(N + 255) / 256, 256, 0, stream>>>(mid, sums, rp_in, N);
  scan_block_kernel<<<nb, 256, 0, stream>>>(hout, mid, sums, N);
  scan_sums_kernel<<<1, 256, 0, stream>>>(sums, nb);
  scan_finalize_kernel<<<(N + 255) / 256, 256, 0, stream>>>(mid, sums, rp_out, N);
  zero_int_kernel<<<(N + 255) / 256, 256, 0, stream>>>(cnt, N);
  fill_kernel<<<(E + 255) / 256, 256, 0, stream>>>(ei, E, 0, E, rp_in, cnt, col_in);
  sort_rows_kernel<<<(N + 255) / 256, 256, 0, stream>>>(rp_in, col_in, N);
  zero_int_kernel<<<(N + 255) / 256, 256, 0, stream>>>(cnt, N);
  fill_kernel<<<(E + 255) / 256, 256, 0, stream>>>(ei, E, E, 0, rp_out, cnt, col_out);
  sort_rows_kernel<<<(N + 255) / 256, 256, 0, stream>>>(rp_out, col_out, N);

  // --- 8 rounds x 2 directions ---
  const int gridMM  = (N + 63) / 64;
  const int gridGRU = (N + 63) / 64;
  const int gridG   = (N + 7) / 8;
  for (int rd = 0; rd < 8; ++rd) {
    for (int dir = 0; dir < 2; ++dir) {
      const int mw = dir ? 3 : 0;
      const int gb = dir ? 10 : 6;   // biases (r,z,ig,hg)
      const int* rp   = dir ? rp_out : rp_in;
      const int* col  = dir ? col_out : col_in;
      const float* iv = dir ? inv_outd : inv_ind;

      // m = MLP(vs) -> t1 (fp32)
      mlp3_kernel<<<gridMM, 256, 0, stream>>>(vs_sp, wf(mw + 0), wf(mw + 1), wf(mw + 2),
                                              bia(mw + 0), bia(mw + 1), bia(mw + 2), t1, N);
      // agg = segsum(t1)/deg -> split-bf16
      gather_kernel<<<gridG, 256, 0, stream>>>(t1, rp, col, iv, agg_sp, N);
      // vs = GRU(agg, vs), in place; weight base = 6 contiguous fragment matrices
      gru_kernel<<<gridGRU, 256, 0, stream>>>(agg_sp, vs_sp, wf(dir ? 12 : 6),
                                              bia(gb + 0), bia(gb + 1), bia(gb + 2), bia(gb + 3),
                                              vs_sp, N);
    }
  }

  final_kernel<<<SVn, 64, 0, stream>>>(vs_sp, sv, pw1, pb1, pw2, pb2, (float*)d_out, SVn);
}

// Round 17
// 2556.637 us; speedup vs baseline: 1.3533x; 1.1217x over previous
//
#include <hip/hip_runtime.h>
#include <math.h>

#define NVTC 7
#define VHS 100
#define CHS 30
#define LDP 112         // t1 (fp32) row stride
#define CTW 128         // padded bias length
#define WFRAG_SZ 32768  // shorts per fragment-ordered weight matrix (hi+lo)
// split-bf16 activation row: 512 B = 128 bf16-hi shorts + 128 bf16-lo shorts (cols 100..127 zero)

typedef short short8 __attribute__((ext_vector_type(8)));
typedef float floatx4 __attribute__((ext_vector_type(4)));

#define MFMA(a, b, c) __builtin_amdgcn_mfma_f32_16x16x32_bf16((a), (b), (c), 0, 0, 0)

// async global->LDS DMA, 16B/lane; LDS dest must be wave-uniform base (+ lane*16 implicit)
#define GLOAD16(g, l)                                                              \
  __builtin_amdgcn_global_load_lds((const __attribute__((address_space(1))) void*)(g), \
                                   (__attribute__((address_space(3))) void*)(l), 16, 0, 0)

__device__ __forceinline__ unsigned short f2bf(float f) {
  unsigned u = __float_as_uint(f);
  return (unsigned short)((u + 0x7fffu + ((u >> 16) & 1u)) >> 16);
}
__device__ __forceinline__ float bf2f(unsigned short h) {
  return __uint_as_float((unsigned)h << 16);
}
// fast gate math: native v_exp/v_rcp (~5 instr vs ~35 libm); err ~1e-6 rel, gates bounded.
__device__ __forceinline__ float sigmf(float v) {
  return __builtin_amdgcn_rcpf(1.f + __expf(-v));
}
__device__ __forceinline__ float tanh_fast(float v) {
  return 1.f - 2.f * __builtin_amdgcn_rcpf(__expf(2.f * v) + 1.f);
}

// ---------------- utility kernels ----------------

__global__ void zero_int_kernel(int* __restrict__ p, int n) {
  int i = blockIdx.x * 256 + threadIdx.x;
  if (i < n) p[i] = 0;
}

__global__ void inv_kernel(const float* __restrict__ ind, const float* __restrict__ outd,
                           float* __restrict__ inv_ind, float* __restrict__ inv_outd, int n) {
  int i = blockIdx.x * 256 + threadIdx.x;
  if (i < n) { inv_ind[i] = 1.0f / ind[i]; inv_outd[i] = 1.0f / outd[i]; }
}

// weight -> fragment-ordered split-bf16 for 16x16x32 MFMA B-operand, ALL 18 matrices in one launch
struct WfragArgs { const float* src; int srcLD; int colOff; short* dst; };
struct WfragPack { WfragArgs a[18]; };
__global__ void wfrag_all_kernel(WfragPack p) {
  const int mat = blockIdx.x >> 3;
  const int t = ((blockIdx.x & 7) << 8) + threadIdx.x;  // 0..2047
  const WfragArgs w = p.a[mat];
  int lane = t & 63, rest = t >> 6;
  int ct = rest & 7, kc = rest >> 3;
  int col = ct * 16 + (lane & 15);
  int kbase = kc * 32 + (lane >> 4) * 8;
  short8 hv, lv;
  #pragma unroll
  for (int i = 0; i < 8; ++i) {
    int k = kbase + i;
    float v = (k < VHS && col < VHS) ? w.src[(size_t)k * w.srcLD + w.colOff + col] : 0.f;
    unsigned short h16 = f2bf(v);
    hv[i] = (short)h16;
    lv[i] = (short)f2bf(v - bf2f(h16));
  }
  int base = ((kc * 8 + ct) * 2 * 64 + lane) * 8;
  *(short8*)(w.dst + base)       = hv;
  *(short8*)(w.dst + base + 512) = lv;
}

// all 14 padded biases in one launch
struct PadArgs { const float* b1; int off1; const float* b2; int off2; float* dst; };
struct PadPack { PadArgs a[14]; };
__global__ void pad_all_kernel(PadPack p) {
  const PadArgs w = p.a[blockIdx.x];
  int c = threadIdx.x;  // 128 threads
  float v = 0.f;
  if (c < VHS) { v = w.b1[w.off1 + c]; if (w.b2) v += w.b2[w.off2 + c]; }
  w.dst[c] = v;
}

// vs0 = x @ type_vec, written in split-bf16 row format (cols >= 100 zero)
__global__ void init_vs_kernel(const float* __restrict__ x, const float* __restrict__ tv,
                               char* __restrict__ vsp, int N) {
  int node = blockIdx.x, c = threadIdx.x;  // 128 threads
  if (node >= N) return;
  float v = 0.f;
  if (c < VHS) {
    #pragma unroll
    for (int t = 0; t < NVTC; ++t) v += x[(size_t)node * NVTC + t] * tv[t * VHS + c];
  }
  unsigned short hi = f2bf(v);
  unsigned short lo = f2bf(v - bf2f(hi));
  char* rowp = vsp + ((size_t)node << 9);
  *(unsigned short*)(rowp + 2 * c)       = hi;
  *(unsigned short*)(rowp + 256 + 2 * c) = lo;
}

// ---------------- CSR build (deterministic) ----------------

__global__ void hist_kernel(const int* __restrict__ ei, int E, int* hin, int* hout) {
  int e = blockIdx.x * 256 + threadIdx.x;
  if (e < E) {
    atomicAdd(&hout[ei[e]], 1);
    atomicAdd(&hin[ei[E + e]], 1);
  }
}

__global__ void scan_block_kernel(const int* __restrict__ in, int* __restrict__ mid,
                                  int* __restrict__ sums, int n) {
  __shared__ int lds[256];
  int tid = threadIdx.x;
  int base = blockIdx.x * 1024 + tid * 4;
  int v0 = (base + 0 < n) ? in[base + 0] : 0;
  int v1 = (base + 1 < n) ? in[base + 1] : 0;
  int v2 = (base + 2 < n) ? in[base + 2] : 0;
  int v3 = (base + 3 < n) ? in[base + 3] : 0;
  int s = v0 + v1 + v2 + v3;
  lds[tid] = s;
  __syncthreads();
  for (int off = 1; off < 256; off <<= 1) {
    int t = (tid >= off) ? lds[tid - off] : 0;
    __syncthreads();
    lds[tid] += t;
    __syncthreads();
  }
  int excl = lds[tid] - s;
  int e0 = excl + v0, e1 = e0 + v1, e2 = e1 + v2, e3 = e2 + v3;
  if (base + 0 < n) mid[base + 0] = e0;
  if (base + 1 < n) mid[base + 1] = e1;
  if (base + 2 < n) mid[base + 2] = e2;
  if (base + 3 < n) mid[base + 3] = e3;
  if (tid == 255) sums[blockIdx.x] = lds[255];
}

__global__ void scan_sums_kernel(int* sums, int nb) {
  __shared__ int lds[256];
  int tid = threadIdx.x;
  int v = (tid < nb) ? sums[tid] : 0;
  lds[tid] = v;
  __syncthreads();
  for (int off = 1; off < 256; off <<= 1) {
    int t = (tid >= off) ? lds[tid - off] : 0;
    __syncthreads();
    lds[tid] += t;
    __syncthreads();
  }
  if (tid < nb) sums[tid] = lds[tid];
}

__global__ void scan_finalize_kernel(const int* __restrict__ mid, const int* __restrict__ sums,
                                     int* __restrict__ rp, int n) {
  int i = blockIdx.x * 256 + threadIdx.x;
  if (i >= n) return;
  int blk = i >> 10;
  int add = (blk > 0) ? sums[blk - 1] : 0;
  rp[i + 1] = mid[i] + add;
  if (i == 0) rp[0] = 0;
}

__global__ void fill_kernel(const int* __restrict__ ei, int E, int gOff, int sOff,
                            const int* __restrict__ rp, int* cnt, int* col) {
  int e = blockIdx.x * 256 + threadIdx.x;
  if (e >= E) return;
  int v = ei[sOff + e];
  int p = rp[v] + atomicAdd(&cnt[v], 1);
  col[p] = ei[gOff + e];
}

__global__ void sort_rows_kernel(const int* __restrict__ rp, int* col, int n) {
  int v = blockIdx.x * 256 + threadIdx.x;
  if (v >= n) return;
  int a = rp[v], b = rp[v + 1];
  for (int i = a + 1; i < b; ++i) {
    int key = col[i];
    int j = i - 1;
    while (j >= a && col[j] > key) { col[j + 1] = col[j]; --j; }
    col[j + 1] = key;
  }
}

// agg[v] = (sum of m[u] over sorted neighbors) * iv[v], written split-bf16.
__global__ void __launch_bounds__(256)
gather_kernel(const float* __restrict__ m, const int* __restrict__ rp,
              const int* __restrict__ col, const float* __restrict__ iv,
              char* __restrict__ aggp, int N) {
  int v = blockIdx.x * 8 + (threadIdx.x >> 5);
  if (v >= N) return;
  int lane = threadIdx.x & 31;
  char* rowp = aggp + ((size_t)v << 9);
  if (lane < 28) {
    float4 a = make_float4(0.f, 0.f, 0.f, 0.f);
    int s = rp[v], e = rp[v + 1];
    for (int i = s; i < e; ++i) {
      float4 u = ((const float4*)(m + (size_t)col[i] * LDP))[lane];
      a.x += u.x; a.y += u.y; a.z += u.z; a.w += u.w;
    }
    const float sc = iv[v];
    a.x *= sc; a.y *= sc; a.z *= sc; a.w *= sc;
    unsigned short h0 = f2bf(a.x), h1 = f2bf(a.y), h2 = f2bf(a.z), h3 = f2bf(a.w);
    unsigned short l0 = f2bf(a.x - bf2f(h0)), l1 = f2bf(a.y - bf2f(h1));
    unsigned short l2 = f2bf(a.z - bf2f(h2)), l3 = f2bf(a.w - bf2f(h3));
    *(uint2*)(rowp + 8 * lane) =
        make_uint2((unsigned)h0 | ((unsigned)h1 << 16), (unsigned)h2 | ((unsigned)h3 << 16));
    *(uint2*)(rowp + 256 + 8 * lane) =
        make_uint2((unsigned)l0 | ((unsigned)l1 << 16), (unsigned)l2 | ((unsigned)l3 << 16));
  } else {
    *(uint2*)(rowp + 8 * lane)       = make_uint2(0u, 0u);
    *(uint2*)(rowp + 256 + 8 * lane) = make_uint2(0u, 0u);
  }
}

// ---------------- fused MLP (counted-vmcnt LDS weight staging, 4 waves) ----------------
// R16 proven version (see comments there).
__global__ void __launch_bounds__(256, 2)
mlp3_kernel(const char* __restrict__ vsp,
            const short* __restrict__ W1f, const short* __restrict__ W2f,
            const short* __restrict__ W3f,
            const float* __restrict__ b1, const float* __restrict__ b2,
            const float* __restrict__ b3, float* __restrict__ OUT, int N) {
  __shared__ __align__(16) char lds[65536];
  char* ldsH = lds;
  char* ldsL = lds + 16384;
  const int lane = threadIdx.x & 63, wave = threadIdx.x >> 6;
  const int lrbase = wave * 16;
  const int row0 = blockIdx.x * 64 + lrbase;
  const int a_r = lane & 15, a_kg = lane >> 4;
  const int col_l = lane & 15;

  // ---- preloads (drained before the pipeline) ----
  short8 Fh[4], Fl[4];
  {
    const char* vrow = vsp + (((size_t)(row0 + a_r)) << 9) + (a_kg << 4);
    #pragma unroll
    for (int kc = 0; kc < 4; ++kc) {
      Fh[kc] = *(const short8*)(vrow + kc * 64);
      Fl[kc] = *(const short8*)(vrow + 256 + kc * 64);
    }
  }
  float B1[7], B2[7], B3[7];
  #pragma unroll
  for (int ct = 0; ct < 7; ++ct) {
    const int k = ct * 16 + col_l;
    B1[ct] = b1[k]; B2[ct] = b2[k]; B3[ct] = b3[k];
  }
  // zero pad handoff slots k=112..127 for this wave's 16 rows (LDS only)
  if (lane < 32) {
    int row = lrbase + (lane >> 1), sl = 14 + (lane & 1);
    int byte = row * 256 + ((sl * 16) ^ ((row & 7) << 4));
    short8 z = {0, 0, 0, 0, 0, 0, 0, 0};
    *(short8*)(ldsH + byte) = z;
    *(short8*)(ldsL + byte) = z;
  }
  asm volatile("s_waitcnt vmcnt(0)" ::: "memory");

  floatx4 acc[7];
  #pragma unroll
  for (int c = 0; c < 7; ++c) acc[c] = (floatx4){0.f, 0.f, 0.f, 0.f};

#define MSTAGE(WF, KC, BOFF)                                                   \
  {                                                                            \
    _Pragma("unroll") for (int q = 0; q < 4; ++q) {                            \
      const int c_ = wave * 4 + q;                                             \
      GLOAD16((const char*)(WF) + (size_t)((KC) * 16384 + c_ * 1024) + lane * 16, \
              lds + (BOFF) + c_ * 1024);                                       \
    }                                                                          \
  }

#define MCOMP(KC, BOFF, VA)                                                    \
  {                                                                            \
    asm volatile("s_waitcnt vmcnt(" VA ")" ::: "memory");                      \
    __builtin_amdgcn_s_barrier();                                              \
    short8 wt[14];                                                             \
    _Pragma("unroll") for (int c = 0; c < 7; ++c) {                            \
      wt[2 * c]     = *(const short8*)(lds + (BOFF) + (2 * c) * 1024 + lane * 16); \
      wt[2 * c + 1] = *(const short8*)(lds + (BOFF) + (2 * c + 1) * 1024 + lane * 16); \
    }                                                                          \
    __builtin_amdgcn_s_setprio(1);                                             \
    _Pragma("unroll") for (int c = 0; c < 7; ++c) {                            \
      acc[c] = MFMA(Fh[KC], wt[2 * c], acc[c]);                                \
      acc[c] = MFMA(Fh[KC], wt[2 * c + 1], acc[c]);                            \
      acc[c] = MFMA(Fl[KC], wt[2 * c], acc[c]);                                \
    }                                                                          \
    __builtin_amdgcn_s_setprio(0);                                             \
    __builtin_amdgcn_sched_barrier(0);                                         \
    __builtin_amdgcn_s_barrier();                                              \
  }

  auto wbrelu = [&](const float* B) {
    const int rloc0 = lrbase + (lane >> 4) * 4;
    #pragma unroll
    for (int ct = 0; ct < 7; ++ct) {
      int k = ct * 16 + col_l;
      #pragma unroll
      for (int j = 0; j < 4; ++j) {
        int row = rloc0 + j;
        float v = fmaxf(acc[ct][j] + B[ct], 0.f);
        unsigned short h16 = f2bf(v);
        unsigned short l16 = f2bf(v - bf2f(h16));
        int byte = row * 256 + ((k * 2) ^ ((row & 7) << 4));
        *(short*)(ldsH + byte) = (short)h16;
        *(short*)(ldsL + byte) = (short)l16;
      }
      acc[ct] = (floatx4){0.f, 0.f, 0.f, 0.f};
    }
  };
  auto ldfrags = [&]() {
    #pragma unroll
    for (int kc = 0; kc < 4; ++kc) {
      int r = lrbase + a_r;
      int byte = r * 256 + ((((kc * 4 + a_kg) * 16)) ^ ((r & 7) << 4));
      Fh[kc] = *(const short8*)(ldsH + byte);
      Fl[kc] = *(const short8*)(ldsL + byte);
    }
  };

  // 12-slice static pipeline; WA @32768, WB @49152
  MSTAGE(W1f, 0, 32768) MSTAGE(W1f, 1, 49152)
  MCOMP(0, 32768, "4")  MSTAGE(W1f, 2, 32768)
  MCOMP(1, 49152, "4")  MSTAGE(W1f, 3, 49152)
  MCOMP(2, 32768, "4")  MSTAGE(W2f, 0, 32768)
  MCOMP(3, 49152, "4")  MSTAGE(W2f, 1, 49152)
  wbrelu(B1); ldfrags();
  MCOMP(0, 32768, "4")  MSTAGE(W2f, 2, 32768)
  MCOMP(1, 49152, "4")  MSTAGE(W2f, 3, 49152)
  MCOMP(2, 32768, "4")  MSTAGE(W3f, 0, 32768)
  MCOMP(3, 49152, "4")  MSTAGE(W3f, 1, 49152)
  wbrelu(B2); ldfrags();
  MCOMP(0, 32768, "4")  MSTAGE(W3f, 2, 32768)
  MCOMP(1, 49152, "4")  MSTAGE(W3f, 3, 49152)
  MCOMP(2, 32768, "4")
  MCOMP(3, 49152, "0")

  // epilogue: linear + bias -> t1 (fp32); after final wait, guards are ledger-safe
  const int r0 = row0 + (lane >> 4) * 4;
  #pragma unroll
  for (int ct = 0; ct < 7; ++ct) {
    const int c = ct * 16 + col_l;
    #pragma unroll
    for (int j = 0; j < 4; ++j) {
      const int r = r0 + j;
      if (r < N) OUT[(size_t)r * LDP + c] = acc[ct][j] + B3[ct];
    }
  }
#undef MSTAGE
#undef MCOMP
}

// ---------------- fused GRU (counted-vmcnt double-buffered LDS weight staging) ----------------
// R14/R16 proven version; only change: fast native sigmoid/tanh in the epilogue.
__global__ void __launch_bounds__(256, 2)
gru_kernel(const char* __restrict__ aggp, const char* __restrict__ vsp,
           const short* __restrict__ Wbase,
           const float* __restrict__ br, const float* __restrict__ bz,
           const float* __restrict__ big, const float* __restrict__ bhg,
           char* __restrict__ outp, int N) {
  __shared__ __align__(16) char wlds[49152];  // buf0 @0, buf1 @24576
  const int lane = threadIdx.x & 63, wave = threadIdx.x >> 6;
  const int row0 = blockIdx.x * 64 + wave * 16;
  const int a_r = lane & 15;
  const int kgo = (lane >> 4) << 4;
  const int col_l = lane & 15;
  const int jr0 = row0 + (lane >> 4) * 4;

  // ---- preloads (all drained before the pipeline starts) ----
  short8 Ah[4], Al[4], Vh[4], Vl[4];
  {
    const char* arow = aggp + (((size_t)(row0 + a_r)) << 9) + kgo;
    const char* vrow = vsp  + (((size_t)(row0 + a_r)) << 9) + kgo;
    #pragma unroll
    for (int kc = 0; kc < 4; ++kc) {
      Ah[kc] = *(const short8*)(arow + kc * 64);
      Al[kc] = *(const short8*)(arow + 256 + kc * 64);
      Vh[kc] = *(const short8*)(vrow + kc * 64);
      Vl[kc] = *(const short8*)(vrow + 256 + kc * 64);
    }
  }
  float ho[7][4];
  #pragma unroll
  for (int ct = 0; ct < 7; ++ct) {
    const int ccol = ct * 16 + col_l;
    #pragma unroll
    for (int j = 0; j < 4; ++j) {
      const char* hrow = vsp + ((size_t)(jr0 + j) << 9);
      ho[ct][j] = bf2f(*(const unsigned short*)(hrow + 2 * ccol)) +
                  bf2f(*(const unsigned short*)(hrow + 256 + 2 * ccol));
    }
  }
  float bR[7], bZ[7], bI[7], bH[7];
  #pragma unroll
  for (int ct = 0; ct < 7; ++ct) {
    const int ccol = ct * 16 + col_l;
    bR[ct] = br[ccol]; bZ[ct] = bz[ccol]; bI[ct] = big[ccol]; bH[ct] = bhg[ccol];
  }
  asm volatile("s_waitcnt vmcnt(0)" ::: "memory");

#define GRU_STAGE(CT, KH, BOFF)                                                \
  {                                                                            \
    _Pragma("unroll") for (int q = 0; q < 6; ++q) {                            \
      const int c_ = wave * 6 + q;                                             \
      const int m_ = c_ >> 2, kcl_ = (c_ >> 1) & 1, p_ = c_ & 1;               \
      const size_t gb_ = (size_t)m_ * 65536 +                                  \
          (size_t)(((((KH) * 2 + kcl_) * 8 + (CT)) * 2048) + p_ * 1024);       \
      GLOAD16((const char*)Wbase + gb_ + lane * 16, wlds + (BOFF) + c_ * 1024);\
    }                                                                          \
  }

#define GRU_HALF(KH, BOFF)                                                     \
  {                                                                            \
    _Pragma("unroll") for (int kcl = 0; kcl < 2; ++kcl) {                      \
      const int kc_ = (KH) * 2 + kcl;                                          \
      short8 wt[12];                                                           \
      _Pragma("unroll") for (int mp = 0; mp < 12; ++mp) {                      \
        const int m_ = mp >> 1, p_ = mp & 1;                                   \
        const int chunk_ = m_ * 4 + kcl * 2 + p_;                              \
        wt[mp] = *(const short8*)(wlds + (BOFF) + chunk_ * 1024 + lane * 16);  \
      }                                                                        \
      __builtin_amdgcn_s_setprio(1);                                           \
      rc = MFMA(Ah[kc_], wt[0], rc);  rc = MFMA(Ah[kc_], wt[1], rc);  rc = MFMA(Al[kc_], wt[0], rc); \
      zc = MFMA(Ah[kc_], wt[2], zc);  zc = MFMA(Ah[kc_], wt[3], zc);  zc = MFMA(Al[kc_], wt[2], zc); \
      ic = MFMA(Ah[kc_], wt[4], ic);  ic = MFMA(Ah[kc_], wt[5], ic);  ic = MFMA(Al[kc_], wt[4], ic); \
      rc = MFMA(Vh[kc_], wt[6], rc);  rc = MFMA(Vh[kc_], wt[7], rc);  rc = MFMA(Vl[kc_], wt[6], rc); \
      zc = MFMA(Vh[kc_], wt[8], zc);  zc = MFMA(Vh[kc_], wt[9], zc);  zc = MFMA(Vl[kc_], wt[8], zc); \
      hc = MFMA(Vh[kc_], wt[10], hc); hc = MFMA(Vh[kc_], wt[11], hc); hc = MFMA(Vl[kc_], wt[10], hc); \
      __builtin_amdgcn_s_setprio(0);                                           \
    }                                                                          \
  }

#define GRU_ITER(CT, VA, VB, STG)                                              \
  {                                                                            \
    floatx4 rc = {0.f, 0.f, 0.f, 0.f};                                         \
    floatx4 zc = {0.f, 0.f, 0.f, 0.f};                                         \
    floatx4 ic = {0.f, 0.f, 0.f, 0.f};                                         \
    floatx4 hc = {0.f, 0.f, 0.f, 0.f};                                         \
    asm volatile("s_waitcnt vmcnt(" VA ")" ::: "memory");                      \
    __builtin_amdgcn_s_barrier();                                              \
    GRU_HALF(0, 0)                                                             \
    __builtin_amdgcn_sched_barrier(0);                                         \
    __builtin_amdgcn_s_barrier();                                              \
    if (STG) GRU_STAGE((CT) + 1, 0, 0)                                         \
    asm volatile("s_waitcnt vmcnt(" VB ")" ::: "memory");                      \
    __builtin_amdgcn_s_barrier();                                              \
    GRU_HALF(1, 24576)                                                         \
    __builtin_amdgcn_sched_barrier(0);                                         \
    __builtin_amdgcn_s_barrier();                                              \
    if (STG) GRU_STAGE((CT) + 1, 1, 24576)                                     \
    const float brv = bR[CT], bzv = bZ[CT], bigv = bI[CT], bhgv = bH[CT];      \
    const int ccol = (CT) * 16 + col_l;                                        \
    _Pragma("unroll") for (int j = 0; j < 4; ++j) {                            \
      const float rv = sigmf(rc[j] + brv);                                     \
      const float zv = sigmf(zc[j] + bzv);                                     \
      const float gv = tanh_fast(ic[j] + bigv + rv * (hc[j] + bhgv));          \
      const float v = (1.f - zv) * gv + zv * ho[CT][j];                        \
      const unsigned short hi = f2bf(v);                                       \
      const unsigned short lo = f2bf(v - bf2f(hi));                            \
      char* orow = outp + ((size_t)(jr0 + j) << 9);                            \
      *(unsigned short*)(orow + 2 * ccol)       = hi;                          \
      *(unsigned short*)(orow + 256 + 2 * ccol) = lo;                          \
    }                                                                          \
  }

  // prologue: both halves of ct=0 in flight (12 outstanding)
  GRU_STAGE(0, 0, 0)
  GRU_STAGE(0, 1, 24576)

  GRU_ITER(0, "6",  "6",  1)
  GRU_ITER(1, "14", "14", 1)
  GRU_ITER(2, "14", "14", 1)
  GRU_ITER(3, "14", "14", 1)
  GRU_ITER(4, "14", "14", 1)
  GRU_ITER(5, "14", "14", 1)
  GRU_ITER(6, "14", "8",  0)

#undef GRU_STAGE
#undef GRU_HALF
#undef GRU_ITER
}

// ---------------- final projection ----------------
__global__ void final_kernel(const char* __restrict__ vsp, const int* __restrict__ sv,
                             const float* __restrict__ pw1, const float* __restrict__ pb1,
                             const float* __restrict__ pw2, const float* __restrict__ pb2,
                             float* __restrict__ out, int SVn) {
  int b = blockIdx.x;
  if (b >= SVn) return;
  int tid = threadIdx.x;  // 64
  int node = sv[b];
  const char* rowp = vsp + ((size_t)node << 9);
  float p = 0.f;
  if (tid < CHS) {
    float acc = 0.f;
    for (int k = 0; k < VHS; ++k) {
      float xv = bf2f(*(const unsigned short*)(rowp + 2 * k)) +
                 bf2f(*(const unsigned short*)(rowp + 256 + 2 * k));
      acc += xv * pw1[k * CHS + tid];
    }
    float h = fmaxf(acc + pb1[tid], 0.f);
    p = h * pw2[tid];
  }
  #pragma unroll
  for (int off = 32; off > 0; off >>= 1) p += __shfl_down(p, off);
  if (tid == 0) out[b] = p + pb2[0];
}

// ---------------- launcher ----------------
extern "C" void kernel_launch(void* const* d_in, const int* in_sizes, int n_in,
                              void* d_out, int out_size, void* d_ws, size_t ws_size,
                              hipStream_t stream) {
  const float* x      = (const float*)d_in[0];
  const int*   ei     = (const int*)d_in[1];
  const int*   sv     = (const int*)d_in[2];
  const float* ind    = (const float*)d_in[3];
  const float* outd   = (const float*)d_in[4];
  const float* tv     = (const float*)d_in[7];
  const float* fm_w1  = (const float*)d_in[8];
  const float* fm_b1  = (const float*)d_in[9];
  const float* fm_w2  = (const float*)d_in[10];
  const float* fm_b2  = (const float*)d_in[11];
  const float* fm_w3  = (const float*)d_in[12];
  const float* fm_b3  = (const float*)d_in[13];
  const float* bm_w1  = (const float*)d_in[14];
  const float* bm_b1  = (const float*)d_in[15];
  const float* bm_w2  = (const float*)d_in[16];
  const float* bm_b2  = (const float*)d_in[17];
  const float* bm_w3  = (const float*)d_in[18];
  const float* bm_b3  = (const float*)d_in[19];
  const float* fg_wih = (const float*)d_in[20];
  const float* fg_whh = (const float*)d_in[21];
  const float* fg_bih = (const float*)d_in[22];
  const float* fg_bhh = (const float*)d_in[23];
  const float* bg_wih = (const float*)d_in[24];
  const float* bg_whh = (const float*)d_in[25];
  const float* bg_bih = (const float*)d_in[26];
  const float* bg_bhh = (const float*)d_in[27];
  const float* pw1    = (const float*)d_in[28];
  const float* pb1    = (const float*)d_in[29];
  const float* pw2    = (const float*)d_in[30];
  const float* pb2    = (const float*)d_in[31];

  const int N   = in_sizes[3];
  const int E   = in_sizes[1] / 2;
  const int SVn = in_sizes[2];

  char* wsb = (char*)d_ws;
  const size_t NP = (size_t)N * LDP;
  float* t1     = (float*)wsb;                           // N*112 fp32
  char*  vs_sp  = wsb + NP * 4;                          // (N+256) split rows
  char*  agg_sp = vs_sp + (size_t)(N + 256) * 512;       // (N+256) split rows
  float* inv_ind  = (float*)(agg_sp + (size_t)(N + 256) * 512);
  float* inv_outd = inv_ind + N;
  short* wfrag    = (short*)(inv_outd + N);
  float* biasbase = (float*)(wfrag + 18 * WFRAG_SZ);
  int* ip      = (int*)(biasbase + 14 * CTW);
  int* rp_in   = ip; ip += N + 1;
  int* rp_out  = ip; ip += N + 1;
  int* col_in  = ip; ip += E;
  int* col_out = ip; ip += E;
  int* cnt     = ip; ip += N;
  int* hin     = ip; ip += N;
  int* hout    = ip; ip += N;
  int* mid     = ip; ip += N;
  int* sums    = ip; ip += 512;

  const size_t need_bytes = (size_t)((char*)(ip) - (char*)d_ws);
  if (ws_size < need_bytes) return;

  auto wf  = [&](int i) { return wfrag + (size_t)i * WFRAG_SZ; };
  auto bia = [&](int i) { return biasbase + (size_t)i * CTW; };

  // --- weights -> fragment-ordered split bf16 (single launch, 18 matrices) ---
  WfragPack wp;
  wp.a[0] = {fm_w1, VHS, 0, wf(0)};
  wp.a[1] = {fm_w2, VHS, 0, wf(1)};
  wp.a[2] = {fm_w3, VHS, 0, wf(2)};
  wp.a[3] = {bm_w1, VHS, 0, wf(3)};
  wp.a[4] = {bm_w2, VHS, 0, wf(4)};
  wp.a[5] = {bm_w3, VHS, 0, wf(5)};
  for (int g = 0; g < 3; ++g) {
    wp.a[6 + g]  = {fg_wih, 3 * VHS, g * VHS, wf(6 + g)};
    wp.a[9 + g]  = {fg_whh, 3 * VHS, g * VHS, wf(9 + g)};
    wp.a[12 + g] = {bg_wih, 3 * VHS, g * VHS, wf(12 + g)};
    wp.a[15 + g] = {bg_whh, 3 * VHS, g * VHS, wf(15 + g)};
  }
  wfrag_all_kernel<<<144, 256, 0, stream>>>(wp);

  // --- padded biases (single launch, 14 vectors) ---
  PadPack pp;
  pp.a[0]  = {fm_b1, 0,       nullptr, 0,   bia(0)};
  pp.a[1]  = {fm_b2, 0,       nullptr, 0,   bia(1)};
  pp.a[2]  = {fm_b3, 0,       nullptr, 0,   bia(2)};
  pp.a[3]  = {bm_b1, 0,       nullptr, 0,   bia(3)};
  pp.a[4]  = {bm_b2, 0,       nullptr, 0,   bia(4)};
  pp.a[5]  = {bm_b3, 0,       nullptr, 0,   bia(5)};
  pp.a[6]  = {fg_bih, 0,       fg_bhh, 0,   bia(6)};    // r sum
  pp.a[7]  = {fg_bih, VHS,     fg_bhh, VHS, bia(7)};    // z sum
  pp.a[8]  = {fg_bih, 2 * VHS, nullptr, 0,  bia(8)};    // ig
  pp.a[9]  = {fg_bhh, 2 * VHS, nullptr, 0,  bia(9)};    // hg
  pp.a[10] = {bg_bih, 0,       bg_bhh, 0,   bia(10)};
  pp.a[11] = {bg_bih, VHS,     bg_bhh, VHS, bia(11)};
  pp.a[12] = {bg_bih, 2 * VHS, nullptr, 0,  bia(12)};
  pp.a[13] = {bg_bhh, 2 * VHS, nullptr, 0,  bia(13)};
  pad_all_kernel<<<14, 128, 0, stream>>>(pp);

  inv_kernel<<<(N + 255) / 256, 256, 0, stream>>>(ind, outd, inv_ind, inv_outd, N);
  init_vs_kernel<<<N, 128, 0, stream>>>(x, tv, vs_sp, N);

  // --- CSR build (deterministic via per-row sort) ---
  zero_int_kernel<<<(2 * N + 255) / 256, 256, 0, stream>>>(hin, 2 * N);
  hist_kernel<<<(E + 255) / 256, 256, 0, stream>>>(ei, E, hin, hout);
  const int nb = (N + 1023) / 1024;
  scan_block_kernel<<<nb, 256, 0, stream>>>(hin, mid, sums, N);
  scan_sums_kernel<<<1, 256, 0, stream>>>(sums, nb);
  scan_finalize_kernel<<<(N + 255) / 256, 256, 0, stream>>>(mid, sums, rp_in, N);
  scan_block_kernel<<<nb, 256, 0, stream>>>(hout, mid, sums, N);
  scan_sums_kernel<<<1, 256, 0, stream>>>(sums, nb);
  scan_finalize_kernel<<<(N + 255) / 256, 256, 0, stream>>>(mid, sums, rp_out, N);
  zero_int_kernel<<<(N + 255) / 256, 256, 0, stream>>>(cnt, N);
  fill_kernel<<<(E + 255) / 256, 256, 0, stream>>>(ei, E, 0, E, rp_in, cnt, col_in);
  sort_rows_kernel<<<(N + 255) / 256, 256, 0, stream>>>(rp_in, col_in, N);
  zero_int_kernel<<<(N + 255) / 256, 256, 0, stream>>>(cnt, N);
  fill_kernel<<<(E + 255) / 256, 256, 0, stream>>>(ei, E, E, 0, rp_out, cnt, col_out);
  sort_rows_kernel<<<(N + 255) / 256, 256, 0, stream>>>(rp_out, col_out, N);

  // --- 8 rounds x 2 directions ---
  const int gridMM  = (N + 63) / 64;
  const int gridGRU = (N + 63) / 64;
  const int gridG   = (N + 7) / 8;
  for (int rd = 0; rd < 8; ++rd) {
    for (int dir = 0; dir < 2; ++dir) {
      const int mw = dir ? 3 : 0;
      const int gb = dir ? 10 : 6;   // biases (r,z,ig,hg)
      const int* rp   = dir ? rp_out : rp_in;
      const int* col  = dir ? col_out : col_in;
      const float* iv = dir ? inv_outd : inv_ind;

      // m = MLP(vs) -> t1 (fp32)
      mlp3_kernel<<<gridMM, 256, 0, stream>>>(vs_sp, wf(mw + 0), wf(mw + 1), wf(mw + 2),
                                              bia(mw + 0), bia(mw + 1), bia(mw + 2), t1, N);
      // agg = segsum(t1)/deg -> split-bf16
      gather_kernel<<<gridG, 256, 0, stream>>>(t1, rp, col, iv, agg_sp, N);
      // vs = GRU(agg, vs), in place; weight base = 6 contiguous fragment matrices
      gru_kernel<<<gridGRU, 256, 0, stream>>>(agg_sp, vs_sp, wf(dir ? 12 : 6),
                                              bia(gb + 0), bia(gb + 1), bia(gb + 2), bia(gb + 3),
                                              vs_sp, N);
    }
  }

  final_kernel<<<SVn, 64, 0, stream>>>(vs_sp, sv, pw1, pb1, pw2, pb2, (float*)d_out, SVn);
}

// Round 18
// 2505.122 us; speedup vs baseline: 1.3812x; 1.0206x over previous
//
#include <hip/hip_runtime.h>
#include <math.h>

#define NVTC 7
#define VHS 100
#define CHS 30
#define LDP 112         // t1 (fp32) row stride
#define CTW 128         // padded bias length
#define WFRAG_SZ 32768  // shorts per fragment-ordered weight matrix (hi+lo)
// split-bf16 activation row: 512 B = 128 bf16-hi shorts + 128 bf16-lo shorts (cols 100..127 zero)

typedef short short8 __attribute__((ext_vector_type(8)));
typedef float floatx4 __attribute__((ext_vector_type(4)));

#define MFMA(a, b, c) __builtin_amdgcn_mfma_f32_16x16x32_bf16((a), (b), (c), 0, 0, 0)

// async global->LDS DMA, 16B/lane; LDS dest must be wave-uniform base (+ lane*16 implicit)
#define GLOAD16(g, l)                                                              \
  __builtin_amdgcn_global_load_lds((const __attribute__((address_space(1))) void*)(g), \
                                   (__attribute__((address_space(3))) void*)(l), 16, 0, 0)

__device__ __forceinline__ unsigned short f2bf(float f) {
  unsigned u = __float_as_uint(f);
  return (unsigned short)((u + 0x7fffu + ((u >> 16) & 1u)) >> 16);
}
__device__ __forceinline__ float bf2f(unsigned short h) {
  return __uint_as_float((unsigned)h << 16);
}
// fast gate math: native v_exp/v_rcp (~5 instr vs ~35 libm); err ~1e-6 rel, gates bounded.
__device__ __forceinline__ float sigmf(float v) {
  return __builtin_amdgcn_rcpf(1.f + __expf(-v));
}
__device__ __forceinline__ float tanh_fast(float v) {
  return 1.f - 2.f * __builtin_amdgcn_rcpf(__expf(2.f * v) + 1.f);
}

// ---------------- utility kernels ----------------

__global__ void zero_int_kernel(int* __restrict__ p, int n) {
  int i = blockIdx.x * 256 + threadIdx.x;
  if (i < n) p[i] = 0;
}

__global__ void inv_kernel(const float* __restrict__ ind, const float* __restrict__ outd,
                           float* __restrict__ inv_ind, float* __restrict__ inv_outd, int n) {
  int i = blockIdx.x * 256 + threadIdx.x;
  if (i < n) { inv_ind[i] = 1.0f / ind[i]; inv_outd[i] = 1.0f / outd[i]; }
}

// weight -> fragment-ordered split-bf16 for 16x16x32 MFMA B-operand, ALL 18 matrices in one launch
struct WfragArgs { const float* src; int srcLD; int colOff; short* dst; };
struct WfragPack { WfragArgs a[18]; };
__global__ void wfrag_all_kernel(WfragPack p) {
  const int mat = blockIdx.x >> 3;
  const int t = ((blockIdx.x & 7) << 8) + threadIdx.x;  // 0..2047
  const WfragArgs w = p.a[mat];
  int lane = t & 63, rest = t >> 6;
  int ct = rest & 7, kc = rest >> 3;
  int col = ct * 16 + (lane & 15);
  int kbase = kc * 32 + (lane >> 4) * 8;
  short8 hv, lv;
  #pragma unroll
  for (int i = 0; i < 8; ++i) {
    int k = kbase + i;
    float v = (k < VHS && col < VHS) ? w.src[(size_t)k * w.srcLD + w.colOff + col] : 0.f;
    unsigned short h16 = f2bf(v);
    hv[i] = (short)h16;
    lv[i] = (short)f2bf(v - bf2f(h16));
  }
  int base = ((kc * 8 + ct) * 2 * 64 + lane) * 8;
  *(short8*)(w.dst + base)       = hv;
  *(short8*)(w.dst + base + 512) = lv;
}

// all 14 padded biases in one launch
struct PadArgs { const float* b1; int off1; const float* b2; int off2; float* dst; };
struct PadPack { PadArgs a[14]; };
__global__ void pad_all_kernel(PadPack p) {
  const PadArgs w = p.a[blockIdx.x];
  int c = threadIdx.x;  // 128 threads
  float v = 0.f;
  if (c < VHS) { v = w.b1[w.off1 + c]; if (w.b2) v += w.b2[w.off2 + c]; }
  w.dst[c] = v;
}

// vs0 = x @ type_vec, written in split-bf16 row format (cols >= 100 zero)
__global__ void init_vs_kernel(const float* __restrict__ x, const float* __restrict__ tv,
                               char* __restrict__ vsp, int N) {
  int node = blockIdx.x, c = threadIdx.x;  // 128 threads
  if (node >= N) return;
  float v = 0.f;
  if (c < VHS) {
    #pragma unroll
    for (int t = 0; t < NVTC; ++t) v += x[(size_t)node * NVTC + t] * tv[t * VHS + c];
  }
  unsigned short hi = f2bf(v);
  unsigned short lo = f2bf(v - bf2f(hi));
  char* rowp = vsp + ((size_t)node << 9);
  *(unsigned short*)(rowp + 2 * c)       = hi;
  *(unsigned short*)(rowp + 256 + 2 * c) = lo;
}

// ---------------- CSR build (deterministic) ----------------

__global__ void hist_kernel(const int* __restrict__ ei, int E, int* hin, int* hout) {
  int e = blockIdx.x * 256 + threadIdx.x;
  if (e < E) {
    atomicAdd(&hout[ei[e]], 1);
    atomicAdd(&hin[ei[E + e]], 1);
  }
}

__global__ void scan_block_kernel(const int* __restrict__ in, int* __restrict__ mid,
                                  int* __restrict__ sums, int n) {
  __shared__ int lds[256];
  int tid = threadIdx.x;
  int base = blockIdx.x * 1024 + tid * 4;
  int v0 = (base + 0 < n) ? in[base + 0] : 0;
  int v1 = (base + 1 < n) ? in[base + 1] : 0;
  int v2 = (base + 2 < n) ? in[base + 2] : 0;
  int v3 = (base + 3 < n) ? in[base + 3] : 0;
  int s = v0 + v1 + v2 + v3;
  lds[tid] = s;
  __syncthreads();
  for (int off = 1; off < 256; off <<= 1) {
    int t = (tid >= off) ? lds[tid - off] : 0;
    __syncthreads();
    lds[tid] += t;
    __syncthreads();
  }
  int excl = lds[tid] - s;
  int e0 = excl + v0, e1 = e0 + v1, e2 = e1 + v2, e3 = e2 + v3;
  if (base + 0 < n) mid[base + 0] = e0;
  if (base + 1 < n) mid[base + 1] = e1;
  if (base + 2 < n) mid[base + 2] = e2;
  if (base + 3 < n) mid[base + 3] = e3;
  if (tid == 255) sums[blockIdx.x] = lds[255];
}

__global__ void scan_sums_kernel(int* sums, int nb) {
  __shared__ int lds[256];
  int tid = threadIdx.x;
  int v = (tid < nb) ? sums[tid] : 0;
  lds[tid] = v;
  __syncthreads();
  for (int off = 1; off < 256; off <<= 1) {
    int t = (tid >= off) ? lds[tid - off] : 0;
    __syncthreads();
    lds[tid] += t;
    __syncthreads();
  }
  if (tid < nb) sums[tid] = lds[tid];
}

__global__ void scan_finalize_kernel(const int* __restrict__ mid, const int* __restrict__ sums,
                                     int* __restrict__ rp, int n) {
  int i = blockIdx.x * 256 + threadIdx.x;
  if (i >= n) return;
  int blk = i >> 10;
  int add = (blk > 0) ? sums[blk - 1] : 0;
  rp[i + 1] = mid[i] + add;
  if (i == 0) rp[0] = 0;
}

__global__ void fill_kernel(const int* __restrict__ ei, int E, int gOff, int sOff,
                            const int* __restrict__ rp, int* cnt, int* col) {
  int e = blockIdx.x * 256 + threadIdx.x;
  if (e >= E) return;
  int v = ei[sOff + e];
  int p = rp[v] + atomicAdd(&cnt[v], 1);
  col[p] = ei[gOff + e];
}

__global__ void sort_rows_kernel(const int* __restrict__ rp, int* col, int n) {
  int v = blockIdx.x * 256 + threadIdx.x;
  if (v >= n) return;
  int a = rp[v], b = rp[v + 1];
  for (int i = a + 1; i < b; ++i) {
    int key = col[i];
    int j = i - 1;
    while (j >= a && col[j] > key) { col[j + 1] = col[j]; --j; }
    col[j + 1] = key;
  }
}

// agg[v] = (sum of m[u] over sorted neighbors) * iv[v], written split-bf16.
// 2-wide unrolled neighbor loop: two independent col->row load chains in flight
// (latency-bound dependent chain was the bottleneck; mean degree 4 -> 2 unrolled iters).
__global__ void __launch_bounds__(256)
gather_kernel(const float* __restrict__ m, const int* __restrict__ rp,
              const int* __restrict__ col, const float* __restrict__ iv,
              char* __restrict__ aggp, int N) {
  int v = blockIdx.x * 8 + (threadIdx.x >> 5);
  if (v >= N) return;
  int lane = threadIdx.x & 31;
  char* rowp = aggp + ((size_t)v << 9);
  if (lane < 28) {
    float4 a = make_float4(0.f, 0.f, 0.f, 0.f);
    float4 b = make_float4(0.f, 0.f, 0.f, 0.f);
    const int s = rp[v], e = rp[v + 1];
    int i = s;
    for (; i + 1 < e; i += 2) {
      const int c0 = col[i], c1 = col[i + 1];
      float4 u = ((const float4*)(m + (size_t)c0 * LDP))[lane];
      float4 w = ((const float4*)(m + (size_t)c1 * LDP))[lane];
      a.x += u.x; a.y += u.y; a.z += u.z; a.w += u.w;
      b.x += w.x; b.y += w.y; b.z += w.z; b.w += w.w;
    }
    if (i < e) {
      float4 u = ((const float4*)(m + (size_t)col[i] * LDP))[lane];
      a.x += u.x; a.y += u.y; a.z += u.z; a.w += u.w;
    }
    a.x += b.x; a.y += b.y; a.z += b.z; a.w += b.w;
    const float sc = iv[v];
    a.x *= sc; a.y *= sc; a.z *= sc; a.w *= sc;
    unsigned short h0 = f2bf(a.x), h1 = f2bf(a.y), h2 = f2bf(a.z), h3 = f2bf(a.w);
    unsigned short l0 = f2bf(a.x - bf2f(h0)), l1 = f2bf(a.y - bf2f(h1));
    unsigned short l2 = f2bf(a.z - bf2f(h2)), l3 = f2bf(a.w - bf2f(h3));
    *(uint2*)(rowp + 8 * lane) =
        make_uint2((unsigned)h0 | ((unsigned)h1 << 16), (unsigned)h2 | ((unsigned)h3 << 16));
    *(uint2*)(rowp + 256 + 8 * lane) =
        make_uint2((unsigned)l0 | ((unsigned)l1 << 16), (unsigned)l2 | ((unsigned)l3 << 16));
  } else {
    *(uint2*)(rowp + 8 * lane)       = make_uint2(0u, 0u);
    *(uint2*)(rowp + 256 + 8 * lane) = make_uint2(0u, 0u);
  }
}

// ---------------- fused MLP (counted-vmcnt LDS weight staging, 4 waves) ----------------
// R16 proven version (see comments there).
__global__ void __launch_bounds__(256, 2)
mlp3_kernel(const char* __restrict__ vsp,
            const short* __restrict__ W1f, const short* __restrict__ W2f,
            const short* __restrict__ W3f,
            const float* __restrict__ b1, const float* __restrict__ b2,
            const float* __restrict__ b3, float* __restrict__ OUT, int N) {
  __shared__ __align__(16) char lds[65536];
  char* ldsH = lds;
  char* ldsL = lds + 16384;
  const int lane = threadIdx.x & 63, wave = threadIdx.x >> 6;
  const int lrbase = wave * 16;
  const int row0 = blockIdx.x * 64 + lrbase;
  const int a_r = lane & 15, a_kg = lane >> 4;
  const int col_l = lane & 15;

  // ---- preloads (drained before the pipeline) ----
  short8 Fh[4], Fl[4];
  {
    const char* vrow = vsp + (((size_t)(row0 + a_r)) << 9) + (a_kg << 4);
    #pragma unroll
    for (int kc = 0; kc < 4; ++kc) {
      Fh[kc] = *(const short8*)(vrow + kc * 64);
      Fl[kc] = *(const short8*)(vrow + 256 + kc * 64);
    }
  }
  float B1[7], B2[7], B3[7];
  #pragma unroll
  for (int ct = 0; ct < 7; ++ct) {
    const int k = ct * 16 + col_l;
    B1[ct] = b1[k]; B2[ct] = b2[k]; B3[ct] = b3[k];
  }
  // zero pad handoff slots k=112..127 for this wave's 16 rows (LDS only)
  if (lane < 32) {
    int row = lrbase + (lane >> 1), sl = 14 + (lane & 1);
    int byte = row * 256 + ((sl * 16) ^ ((row & 7) << 4));
    short8 z = {0, 0, 0, 0, 0, 0, 0, 0};
    *(short8*)(ldsH + byte) = z;
    *(short8*)(ldsL + byte) = z;
  }
  asm volatile("s_waitcnt vmcnt(0)" ::: "memory");

  floatx4 acc[7];
  #pragma unroll
  for (int c = 0; c < 7; ++c) acc[c] = (floatx4){0.f, 0.f, 0.f, 0.f};

#define MSTAGE(WF, KC, BOFF)                                                   \
  {                                                                            \
    _Pragma("unroll") for (int q = 0; q < 4; ++q) {                            \
      const int c_ = wave * 4 + q;                                             \
      GLOAD16((const char*)(WF) + (size_t)((KC) * 16384 + c_ * 1024) + lane * 16, \
              lds + (BOFF) + c_ * 1024);                                       \
    }                                                                          \
  }

#define MCOMP(KC, BOFF, VA)                                                    \
  {                                                                            \
    asm volatile("s_waitcnt vmcnt(" VA ")" ::: "memory");                      \
    __builtin_amdgcn_s_barrier();                                              \
    short8 wt[14];                                                             \
    _Pragma("unroll") for (int c = 0; c < 7; ++c) {                            \
      wt[2 * c]     = *(const short8*)(lds + (BOFF) + (2 * c) * 1024 + lane * 16); \
      wt[2 * c + 1] = *(const short8*)(lds + (BOFF) + (2 * c + 1) * 1024 + lane * 16); \
    }                                                                          \
    __builtin_amdgcn_s_setprio(1);                                             \
    _Pragma("unroll") for (int c = 0; c < 7; ++c) {                            \
      acc[c] = MFMA(Fh[KC], wt[2 * c], acc[c]);                                \
      acc[c] = MFMA(Fh[KC], wt[2 * c + 1], acc[c]);                            \
      acc[c] = MFMA(Fl[KC], wt[2 * c], acc[c]);                                \
    }                                                                          \
    __builtin_amdgcn_s_setprio(0);                                             \
    __builtin_amdgcn_sched_barrier(0);                                         \
    __builtin_amdgcn_s_barrier();                                              \
  }

  auto wbrelu = [&](const float* B) {
    const int rloc0 = lrbase + (lane >> 4) * 4;
    #pragma unroll
    for (int ct = 0; ct < 7; ++ct) {
      int k = ct * 16 + col_l;
      #pragma unroll
      for (int j = 0; j < 4; ++j) {
        int row = rloc0 + j;
        float v = fmaxf(acc[ct][j] + B[ct], 0.f);
        unsigned short h16 = f2bf(v);
        unsigned short l16 = f2bf(v - bf2f(h16));
        int byte = row * 256 + ((k * 2) ^ ((row & 7) << 4));
        *(short*)(ldsH + byte) = (short)h16;
        *(short*)(ldsL + byte) = (short)l16;
      }
      acc[ct] = (floatx4){0.f, 0.f, 0.f, 0.f};
    }
  };
  auto ldfrags = [&]() {
    #pragma unroll
    for (int kc = 0; kc < 4; ++kc) {
      int r = lrbase + a_r;
      int byte = r * 256 + ((((kc * 4 + a_kg) * 16)) ^ ((r & 7) << 4));
      Fh[kc] = *(const short8*)(ldsH + byte);
      Fl[kc] = *(const short8*)(ldsL + byte);
    }
  };

  // 12-slice static pipeline; WA @32768, WB @49152
  MSTAGE(W1f, 0, 32768) MSTAGE(W1f, 1, 49152)
  MCOMP(0, 32768, "4")  MSTAGE(W1f, 2, 32768)
  MCOMP(1, 49152, "4")  MSTAGE(W1f, 3, 49152)
  MCOMP(2, 32768, "4")  MSTAGE(W2f, 0, 32768)
  MCOMP(3, 49152, "4")  MSTAGE(W2f, 1, 49152)
  wbrelu(B1); ldfrags();
  MCOMP(0, 32768, "4")  MSTAGE(W2f, 2, 32768)
  MCOMP(1, 49152, "4")  MSTAGE(W2f, 3, 49152)
  MCOMP(2, 32768, "4")  MSTAGE(W3f, 0, 32768)
  MCOMP(3, 49152, "4")  MSTAGE(W3f, 1, 49152)
  wbrelu(B2); ldfrags();
  MCOMP(0, 32768, "4")  MSTAGE(W3f, 2, 32768)
  MCOMP(1, 49152, "4")  MSTAGE(W3f, 3, 49152)
  MCOMP(2, 32768, "4")
  MCOMP(3, 49152, "0")

  // epilogue: linear + bias -> t1 (fp32); after final wait, guards are ledger-safe
  const int r0 = row0 + (lane >> 4) * 4;
  #pragma unroll
  for (int ct = 0; ct < 7; ++ct) {
    const int c = ct * 16 + col_l;
    #pragma unroll
    for (int j = 0; j < 4; ++j) {
      const int r = r0 + j;
      if (r < N) OUT[(size_t)r * LDP + c] = acc[ct][j] + B3[ct];
    }
  }
#undef MSTAGE
#undef MCOMP
}

// ---------------- fused GRU (counted-vmcnt double-buffered LDS weight staging) ----------------
// R14/R17 proven version: raw s_barrier + counted vmcnt, fast native sigmoid/tanh epilogue.
__global__ void __launch_bounds__(256, 2)
gru_kernel(const char* __restrict__ aggp, const char* __restrict__ vsp,
           const short* __restrict__ Wbase,
           const float* __restrict__ br, const float* __restrict__ bz,
           const float* __restrict__ big, const float* __restrict__ bhg,
           char* __restrict__ outp, int N) {
  __shared__ __align__(16) char wlds[49152];  // buf0 @0, buf1 @24576
  const int lane = threadIdx.x & 63, wave = threadIdx.x >> 6;
  const int row0 = blockIdx.x * 64 + wave * 16;
  const int a_r = lane & 15;
  const int kgo = (lane >> 4) << 4;
  const int col_l = lane & 15;
  const int jr0 = row0 + (lane >> 4) * 4;

  // ---- preloads (all drained before the pipeline starts) ----
  short8 Ah[4], Al[4], Vh[4], Vl[4];
  {
    const char* arow = aggp + (((size_t)(row0 + a_r)) << 9) + kgo;
    const char* vrow = vsp  + (((size_t)(row0 + a_r)) << 9) + kgo;
    #pragma unroll
    for (int kc = 0; kc < 4; ++kc) {
      Ah[kc] = *(const short8*)(arow + kc * 64);
      Al[kc] = *(const short8*)(arow + 256 + kc * 64);
      Vh[kc] = *(const short8*)(vrow + kc * 64);
      Vl[kc] = *(const short8*)(vrow + 256 + kc * 64);
    }
  }
  float ho[7][4];
  #pragma unroll
  for (int ct = 0; ct < 7; ++ct) {
    const int ccol = ct * 16 + col_l;
    #pragma unroll
    for (int j = 0; j < 4; ++j) {
      const char* hrow = vsp + ((size_t)(jr0 + j) << 9);
      ho[ct][j] = bf2f(*(const unsigned short*)(hrow + 2 * ccol)) +
                  bf2f(*(const unsigned short*)(hrow + 256 + 2 * ccol));
    }
  }
  float bR[7], bZ[7], bI[7], bH[7];
  #pragma unroll
  for (int ct = 0; ct < 7; ++ct) {
    const int ccol = ct * 16 + col_l;
    bR[ct] = br[ccol]; bZ[ct] = bz[ccol]; bI[ct] = big[ccol]; bH[ct] = bhg[ccol];
  }
  asm volatile("s_waitcnt vmcnt(0)" ::: "memory");

#define GRU_STAGE(CT, KH, BOFF)                                                \
  {                                                                            \
    _Pragma("unroll") for (int q = 0; q < 6; ++q) {                            \
      const int c_ = wave * 6 + q;                                             \
      const int m_ = c_ >> 2, kcl_ = (c_ >> 1) & 1, p_ = c_ & 1;               \
      const size_t gb_ = (size_t)m_ * 65536 +                                  \
          (size_t)(((((KH) * 2 + kcl_) * 8 + (CT)) * 2048) + p_ * 1024);       \
      GLOAD16((const char*)Wbase + gb_ + lane * 16, wlds + (BOFF) + c_ * 1024);\
    }                                                                          \
  }

#define GRU_HALF(KH, BOFF)                                                     \
  {                                                                            \
    _Pragma("unroll") for (int kcl = 0; kcl < 2; ++kcl) {                      \
      const int kc_ = (KH) * 2 + kcl;                                          \
      short8 wt[12];                                                           \
      _Pragma("unroll") for (int mp = 0; mp < 12; ++mp) {                      \
        const int m_ = mp >> 1, p_ = mp & 1;                                   \
        const int chunk_ = m_ * 4 + kcl * 2 + p_;                              \
        wt[mp] = *(const short8*)(wlds + (BOFF) + chunk_ * 1024 + lane * 16);  \
      }                                                                        \
      __builtin_amdgcn_s_setprio(1);                                           \
      rc = MFMA(Ah[kc_], wt[0], rc);  rc = MFMA(Ah[kc_], wt[1], rc);  rc = MFMA(Al[kc_], wt[0], rc); \
      zc = MFMA(Ah[kc_], wt[2], zc);  zc = MFMA(Ah[kc_], wt[3], zc);  zc = MFMA(Al[kc_], wt[2], zc); \
      ic = MFMA(Ah[kc_], wt[4], ic);  ic = MFMA(Ah[kc_], wt[5], ic);  ic = MFMA(Al[kc_], wt[4], ic); \
      rc = MFMA(Vh[kc_], wt[6], rc);  rc = MFMA(Vh[kc_], wt[7], rc);  rc = MFMA(Vl[kc_], wt[6], rc); \
      zc = MFMA(Vh[kc_], wt[8], zc);  zc = MFMA(Vh[kc_], wt[9], zc);  zc = MFMA(Vl[kc_], wt[8], zc); \
      hc = MFMA(Vh[kc_], wt[10], hc); hc = MFMA(Vh[kc_], wt[11], hc); hc = MFMA(Vl[kc_], wt[10], hc); \
      __builtin_amdgcn_s_setprio(0);                                           \
    }                                                                          \
  }

#define GRU_ITER(CT, VA, VB, STG)                                              \
  {                                                                            \
    floatx4 rc = {0.f, 0.f, 0.f, 0.f};                                         \
    floatx4 zc = {0.f, 0.f, 0.f, 0.f};                                         \
    floatx4 ic = {0.f, 0.f, 0.f, 0.f};                                         \
    floatx4 hc = {0.f, 0.f, 0.f, 0.f};                                         \
    asm volatile("s_waitcnt vmcnt(" VA ")" ::: "memory");                      \
    __builtin_amdgcn_s_barrier();                                              \
    GRU_HALF(0, 0)                                                             \
    __builtin_amdgcn_sched_barrier(0);                                         \
    __builtin_amdgcn_s_barrier();                                              \
    if (STG) GRU_STAGE((CT) + 1, 0, 0)                                         \
    asm volatile("s_waitcnt vmcnt(" VB ")" ::: "memory");                      \
    __builtin_amdgcn_s_barrier();                                              \
    GRU_HALF(1, 24576)                                                         \
    __builtin_amdgcn_sched_barrier(0);                                         \
    __builtin_amdgcn_s_barrier();                                              \
    if (STG) GRU_STAGE((CT) + 1, 1, 24576)                                     \
    const float brv = bR[CT], bzv = bZ[CT], bigv = bI[CT], bhgv = bH[CT];      \
    const int ccol = (CT) * 16 + col_l;                                        \
    _Pragma("unroll") for (int j = 0; j < 4; ++j) {                            \
      const float rv = sigmf(rc[j] + brv);                                     \
      const float zv = sigmf(zc[j] + bzv);                                     \
      const float gv = tanh_fast(ic[j] + bigv + rv * (hc[j] + bhgv));          \
      const float v = (1.f - zv) * gv + zv * ho[CT][j];                        \
      const unsigned short hi = f2bf(v);                                       \
      const unsigned short lo = f2bf(v - bf2f(hi));                            \
      char* orow = outp + ((size_t)(jr0 + j) << 9);                            \
      *(unsigned short*)(orow + 2 * ccol)       = hi;                          \
      *(unsigned short*)(orow + 256 + 2 * ccol) = lo;                          \
    }                                                                          \
  }

  // prologue: both halves of ct=0 in flight (12 outstanding)
  GRU_STAGE(0, 0, 0)
  GRU_STAGE(0, 1, 24576)

  GRU_ITER(0, "6",  "6",  1)
  GRU_ITER(1, "14", "14", 1)
  GRU_ITER(2, "14", "14", 1)
  GRU_ITER(3, "14", "14", 1)
  GRU_ITER(4, "14", "14", 1)
  GRU_ITER(5, "14", "14", 1)
  GRU_ITER(6, "14", "8",  0)

#undef GRU_STAGE
#undef GRU_HALF
#undef GRU_ITER
}

// ---------------- final projection ----------------
__global__ void final_kernel(const char* __restrict__ vsp, const int* __restrict__ sv,
                             const float* __restrict__ pw1, const float* __restrict__ pb1,
                             const float* __restrict__ pw2, const float* __restrict__ pb2,
                             float* __restrict__ out, int SVn) {
  int b = blockIdx.x;
  if (b >= SVn) return;
  int tid = threadIdx.x;  // 64
  int node = sv[b];
  const char* rowp = vsp + ((size_t)node << 9);
  float p = 0.f;
  if (tid < CHS) {
    float acc = 0.f;
    for (int k = 0; k < VHS; ++k) {
      float xv = bf2f(*(const unsigned short*)(rowp + 2 * k)) +
                 bf2f(*(const unsigned short*)(rowp + 256 + 2 * k));
      acc += xv * pw1[k * CHS + tid];
    }
    float h = fmaxf(acc + pb1[tid], 0.f);
    p = h * pw2[tid];
  }
  #pragma unroll
  for (int off = 32; off > 0; off >>= 1) p += __shfl_down(p, off);
  if (tid == 0) out[b] = p + pb2[0];
}

// ---------------- launcher ----------------
extern "C" void kernel_launch(void* const* d_in, const int* in_sizes, int n_in,
                              void* d_out, int out_size, void* d_ws, size_t ws_size,
                              hipStream_t stream) {
  const float* x      = (const float*)d_in[0];
  const int*   ei     = (const int*)d_in[1];
  const int*   sv     = (const int*)d_in[2];
  const float* ind    = (const float*)d_in[3];
  const float* outd   = (const float*)d_in[4];
  const float* tv     = (const float*)d_in[7];
  const float* fm_w1  = (const float*)d_in[8];
  const float* fm_b1  = (const float*)d_in[9];
  const float* fm_w2  = (const float*)d_in[10];
  const float* fm_b2  = (const float*)d_in[11];
  const float* fm_w3  = (const float*)d_in[12];
  const float* fm_b3  = (const float*)d_in[13];
  const float* bm_w1  = (const float*)d_in[14];
  const float* bm_b1  = (const float*)d_in[15];
  const float* bm_w2  = (const float*)d_in[16];
  const float* bm_b2  = (const float*)d_in[17];
  const float* bm_w3  = (const float*)d_in[18];
  const float* bm_b3  = (const float*)d_in[19];
  const float* fg_wih = (const float*)d_in[20];
  const float* fg_whh = (const float*)d_in[21];
  const float* fg_bih = (const float*)d_in[22];
  const float* fg_bhh = (const float*)d_in[23];
  const float* bg_wih = (const float*)d_in[24];
  const float* bg_whh = (const float*)d_in[25];
  const float* bg_bih = (const float*)d_in[26];
  const float* bg_bhh = (const float*)d_in[27];
  const float* pw1    = (const float*)d_in[28];
  const float* pb1    = (const float*)d_in[29];
  const float* pw2    = (const float*)d_in[30];
  const float* pb2    = (const float*)d_in[31];

  const int N   = in_sizes[3];
  const int E   = in_sizes[1] / 2;
  const int SVn = in_sizes[2];

  char* wsb = (char*)d_ws;
  const size_t NP = (size_t)N * LDP;
  float* t1     = (float*)wsb;                           // N*112 fp32
  char*  vs_sp  = wsb + NP * 4;                          // (N+256) split rows
  char*  agg_sp = vs_sp + (size_t)(N + 256) * 512;       // (N+256) split rows
  float* inv_ind  = (float*)(agg_sp + (size_t)(N + 256) * 512);
  float* inv_outd = inv_ind + N;
  short* wfrag    = (short*)(inv_outd + N);
  float* biasbase = (float*)(wfrag + 18 * WFRAG_SZ);
  int* ip      = (int*)(biasbase + 14 * CTW);
  int* rp_in   = ip; ip += N + 1;
  int* rp_out  = ip; ip += N + 1;
  int* col_in  = ip; ip += E;
  int* col_out = ip; ip += E;
  int* cnt     = ip; ip += N;
  int* hin     = ip; ip += N;
  int* hout    = ip; ip += N;
  int* mid     = ip; ip += N;
  int* sums    = ip; ip += 512;

  const size_t need_bytes = (size_t)((char*)(ip) - (char*)d_ws);
  if (ws_size < need_bytes) return;

  auto wf  = [&](int i) { return wfrag + (size_t)i * WFRAG_SZ; };
  auto bia = [&](int i) { return biasbase + (size_t)i * CTW; };

  // --- weights -> fragment-ordered split bf16 (single launch, 18 matrices) ---
  WfragPack wp;
  wp.a[0] = {fm_w1, VHS, 0, wf(0)};
  wp.a[1] = {fm_w2, VHS, 0, wf(1)};
  wp.a[2] = {fm_w3, VHS, 0, wf(2)};
  wp.a[3] = {bm_w1, VHS, 0, wf(3)};
  wp.a[4] = {bm_w2, VHS, 0, wf(4)};
  wp.a[5] = {bm_w3, VHS, 0, wf(5)};
  for (int g = 0; g < 3; ++g) {
    wp.a[6 + g]  = {fg_wih, 3 * VHS, g * VHS, wf(6 + g)};
    wp.a[9 + g]  = {fg_whh, 3 * VHS, g * VHS, wf(9 + g)};
    wp.a[12 + g] = {bg_wih, 3 * VHS, g * VHS, wf(12 + g)};
    wp.a[15 + g] = {bg_whh, 3 * VHS, g * VHS, wf(15 + g)};
  }
  wfrag_all_kernel<<<144, 256, 0, stream>>>(wp);

  // --- padded biases (single launch, 14 vectors) ---
  PadPack pp;
  pp.a[0]  = {fm_b1, 0,       nullptr, 0,   bia(0)};
  pp.a[1]  = {fm_b2, 0,       nullptr, 0,   bia(1)};
  pp.a[2]  = {fm_b3, 0,       nullptr, 0,   bia(2)};
  pp.a[3]  = {bm_b1, 0,       nullptr, 0,   bia(3)};
  pp.a[4]  = {bm_b2, 0,       nullptr, 0,   bia(4)};
  pp.a[5]  = {bm_b3, 0,       nullptr, 0,   bia(5)};
  pp.a[6]  = {fg_bih, 0,       fg_bhh, 0,   bia(6)};    // r sum
  pp.a[7]  = {fg_bih, VHS,     fg_bhh, VHS, bia(7)};    // z sum
  pp.a[8]  = {fg_bih, 2 * VHS, nullptr, 0,  bia(8)};    // ig
  pp.a[9]  = {fg_bhh, 2 * VHS, nullptr, 0,  bia(9)};    // hg
  pp.a[10] = {bg_bih, 0,       bg_bhh, 0,   bia(10)};
  pp.a[11] = {bg_bih, VHS,     bg_bhh, VHS, bia(11)};
  pp.a[12] = {bg_bih, 2 * VHS, nullptr, 0,  bia(12)};
  pp.a[13] = {bg_bhh, 2 * VHS, nullptr, 0,  bia(13)};
  pad_all_kernel<<<14, 128, 0, stream>>>(pp);

  inv_kernel<<<(N + 255) / 256, 256, 0, stream>>>(ind, outd, inv_ind, inv_outd, N);
  init_vs_kernel<<<N, 128, 0, stream>>>(x, tv, vs_sp, N);

  // --- CSR build (deterministic via per-row sort) ---
  zero_int_kernel<<<(2 * N + 255) / 256, 256, 0, stream>>>(hin, 2 * N);
  hist_kernel<<<(E + 255) / 256, 256, 0, stream>>>(ei, E, hin, hout);
  const int nb = (N + 1023) / 1024;
  scan_block_kernel<<<nb, 256, 0, stream>>>(hin, mid, sums, N);
  scan_sums_kernel<<<1, 256, 0, stream>>>(sums, nb);
  scan_finalize_kernel<<<(N + 255) / 256, 256, 0, stream>>>(mid, sums, rp_in, N);
  scan_block_kernel<<<nb, 256, 0, stream>>>(hout, mid, sums, N);
  scan_sums_kernel<<<1, 256, 0, stream>>>(sums, nb);
  scan_finalize_kernel<<<(N + 255) / 256, 256, 0, stream>>>(mid, sums, rp_out, N);
  zero_int_kernel<<<(N + 255) / 256, 256, 0, stream>>>(cnt, N);
  fill_kernel<<<(E + 255) / 256, 256, 0, stream>>>(ei, E, 0, E, rp_in, cnt, col_in);
  sort_rows_kernel<<<(N + 255) / 256, 256, 0, stream>>>(rp_in, col_in, N);
  zero_int_kernel<<<(N + 255) / 256, 256, 0, stream>>>(cnt, N);
  fill_kernel<<<(E + 255) / 256, 256, 0, stream>>>(ei, E, E, 0, rp_out, cnt, col_out);
  sort_rows_kernel<<<(N + 255) / 256, 256, 0, stream>>>(rp_out, col_out, N);

  // --- 8 rounds x 2 directions ---
  const int gridMM  = (N + 63) / 64;
  const int gridGRU = (N + 63) / 64;
  const int gridG   = (N + 7) / 8;
  for (int rd = 0; rd < 8; ++rd) {
    for (int dir = 0; dir < 2; ++dir) {
      const int mw = dir ? 3 : 0;
      const int gb = dir ? 10 : 6;   // biases (r,z,ig,hg)
      const int* rp   = dir ? rp_out : rp_in;
      const int* col  = dir ? col_out : col_in;
      const float* iv = dir ? inv_outd : inv_ind;

      // m = MLP(vs) -> t1 (fp32)
      mlp3_kernel<<<gridMM, 256, 0, stream>>>(vs_sp, wf(mw + 0), wf(mw + 1), wf(mw + 2),
                                              bia(mw + 0), bia(mw + 1), bia(mw + 2), t1, N);
      // agg = segsum(t1)/deg -> split-bf16
      gather_kernel<<<gridG, 256, 0, stream>>>(t1, rp, col, iv, agg_sp, N);
      // vs = GRU(agg, vs), in place; weight base = 6 contiguous fragment matrices
      gru_kernel<<<gridGRU, 256, 0, stream>>>(agg_sp, vs_sp, wf(dir ? 12 : 6),
                                              bia(gb + 0), bia(gb + 1), bia(gb + 2), bia(gb + 3),
                                              vs_sp, N);
    }
  }

  final_kernel<<<SVn, 64, 0, stream>>>(vs_sp, sv, pw1, pb1, pw2, pb2, (float*)d_out, SVn);
}